// Round 1
// baseline (31006.708 us; speedup 1.0000x reference)
//
#include <hip/hip_runtime.h>
#include <cstdint>
#include <cstddef>

// ViT-B/16 + token pruning, fp32 baseline.
// B=64, S=197, D=768, H=12, HD=64, DFF=3072, L=12, prune after 4 -> keep 98(+CLS)=<=99.
// Key insight: pruned/padded tokens never affect the output (attention masks keys,
// everything else is token-local, only CLS is read) -> late blocks run on 99 tokens.

#define NTOK 197
#define NB 64
#define DIM 768
#define NHEAD 12
#define SL 99   // max kept tokens

// ---------------------------------------------------------------- patch extract
__global__ __launch_bounds__(256) void patch_extract_k(const float* __restrict__ img,
                                                       float* __restrict__ out)
{
    int pi = blockIdx.x, b = blockIdx.y;
    int gy = pi / 14, gx = pi % 14;
    size_t obase = ((size_t)b * 196 + pi) * 768;
    for (int f = threadIdx.x; f < 768; f += 256) {
        int c = f >> 8, py = (f >> 4) & 15, px = f & 15;
        out[obase + f] = img[(((size_t)b * 3 + c) * 224 + gy * 16 + py) * 224 + gx * 16 + px];
    }
}

// x[b,0,:] = cls + pos[0]; x[b,1+pi,:] = emb[b,pi,:] + pos[1+pi]
__global__ __launch_bounds__(256) void assemble_k(const float* __restrict__ emb,
                                                  const float* __restrict__ cls,
                                                  const float* __restrict__ pos,
                                                  float* __restrict__ x)
{
    int s = blockIdx.x, b = blockIdx.y;
    size_t xo = ((size_t)b * NTOK + s) * 768;
    for (int d = threadIdx.x; d < 768; d += 256) {
        float v = (s == 0) ? cls[d] : emb[((size_t)b * 196 + (s - 1)) * 768 + d];
        x[xo + d] = v + pos[(size_t)s * 768 + d];
    }
}

// ---------------------------------------------------------------- layernorm (rows of 768)
__global__ __launch_bounds__(256) void ln_k(const float* __restrict__ in, float* __restrict__ out,
                                            const float* __restrict__ g, const float* __restrict__ bt,
                                            size_t ldin, size_t ldout)
{
    const float* xr = in + (size_t)blockIdx.x * ldin;
    float* orow = out + (size_t)blockIdx.x * ldout;
    int t = threadIdx.x;
    float v0 = xr[t], v1 = xr[t + 256], v2 = xr[t + 512];
    float s = v0 + v1 + v2;
#pragma unroll
    for (int o = 32; o; o >>= 1) s += __shfl_xor(s, o);
    __shared__ float r1[4], r2[4];
    int wv = t >> 6, ln = t & 63;
    if (ln == 0) r1[wv] = s;
    __syncthreads();
    float mean = (r1[0] + r1[1] + r1[2] + r1[3]) * (1.f / 768.f);
    float d0 = v0 - mean, d1 = v1 - mean, d2 = v2 - mean;
    float ss = d0 * d0 + d1 * d1 + d2 * d2;
#pragma unroll
    for (int o = 32; o; o >>= 1) ss += __shfl_xor(ss, o);
    if (ln == 0) r2[wv] = ss;
    __syncthreads();
    float inv = rsqrtf((r2[0] + r2[1] + r2[2] + r2[3]) * (1.f / 768.f) + 1e-6f);
    orow[t]       = d0 * inv * g[t]       + bt[t];
    orow[t + 256] = d1 * inv * g[t + 256] + bt[t + 256];
    orow[t + 512] = d2 * inv * g[t + 512] + bt[t + 512];
}

// ---------------------------------------------------------------- fp32 GEMM: C = op(A@W^T + bias [+res])
// A[M,K], W[N,K] row-major. OP: 0 none, 1 exact GELU. RES: add res[M,N].
template<int OP, bool RES>
__global__ __launch_bounds__(256) void gemm_k(const float* __restrict__ A, const float* __restrict__ W,
                                              const float* __restrict__ bias, const float* __restrict__ res,
                                              float* __restrict__ C, int M, int N, int K)
{
    __shared__ float As[16][132];
    __shared__ float Bs[16][132];
    int row0 = blockIdx.y * 128, col0 = blockIdx.x * 128;
    int tid = threadIdx.x;
    int wv = tid >> 6, ln = tid & 63;
    int ms = ((wv >> 1) << 6) | ((ln >> 3) << 3);
    int ns = ((wv & 1) << 6) | ((ln & 7) << 3);
    float acc[8][8];
#pragma unroll
    for (int i = 0; i < 8; i++)
#pragma unroll
        for (int j = 0; j < 8; j++) acc[i][j] = 0.f;

    for (int k0 = 0; k0 < K; k0 += 16) {
#pragma unroll
        for (int q = tid; q < 512; q += 256) {
            int r = q >> 2, kq = (q & 3) << 2;
            int gr = row0 + r;
            float4 av = (gr < M) ? *(const float4*)&A[(size_t)gr * K + k0 + kq]
                                 : make_float4(0.f, 0.f, 0.f, 0.f);
            As[kq + 0][r] = av.x; As[kq + 1][r] = av.y; As[kq + 2][r] = av.z; As[kq + 3][r] = av.w;
            int gn = col0 + r;
            float4 bv = (gn < N) ? *(const float4*)&W[(size_t)gn * K + k0 + kq]
                                 : make_float4(0.f, 0.f, 0.f, 0.f);
            Bs[kq + 0][r] = bv.x; Bs[kq + 1][r] = bv.y; Bs[kq + 2][r] = bv.z; Bs[kq + 3][r] = bv.w;
        }
        __syncthreads();
#pragma unroll
        for (int k = 0; k < 16; k++) {
            float a[8], bb[8];
            *(float4*)&a[0]  = *(const float4*)&As[k][ms];
            *(float4*)&a[4]  = *(const float4*)&As[k][ms + 4];
            *(float4*)&bb[0] = *(const float4*)&Bs[k][ns];
            *(float4*)&bb[4] = *(const float4*)&Bs[k][ns + 4];
#pragma unroll
            for (int i = 0; i < 8; i++)
#pragma unroll
                for (int j = 0; j < 8; j++)
                    acc[i][j] = fmaf(a[i], bb[j], acc[i][j]);
        }
        __syncthreads();
    }

#pragma unroll
    for (int i = 0; i < 8; i++) {
        int r = row0 + ms + i;
        if (r >= M) continue;
        size_t ro = (size_t)r * N;
#pragma unroll
        for (int jq = 0; jq < 8; jq += 4) {
            int c = col0 + ns + jq;
            if (c >= N) continue;          // N%4==0, c%4==0 -> whole quad valid or not
            float4 v;
            v.x = acc[i][jq + 0] + bias[c + 0];
            v.y = acc[i][jq + 1] + bias[c + 1];
            v.z = acc[i][jq + 2] + bias[c + 2];
            v.w = acc[i][jq + 3] + bias[c + 3];
            if (RES) {
                float4 rv = *(const float4*)&res[ro + c];
                v.x += rv.x; v.y += rv.y; v.z += rv.z; v.w += rv.w;
            }
            if (OP == 1) {
                v.x = 0.5f * v.x * (1.f + erff(v.x * 0.70710678118654752f));
                v.y = 0.5f * v.y * (1.f + erff(v.y * 0.70710678118654752f));
                v.z = 0.5f * v.z * (1.f + erff(v.z * 0.70710678118654752f));
                v.w = 0.5f * v.w * (1.f + erff(v.w * 0.70710678118654752f));
            }
            *(float4*)&C[ro + c] = v;
        }
    }
}

// ---------------------------------------------------------------- fused attention per (b,h)
// qkv rows: [S, 2304] with q at h*64, k at 768+h*64, v at 1536+h*64.
// MASKED: only keys < cnt[b] valid; query rows >= cnt get zero output.
template<bool MASKED>
__global__ __launch_bounds__(256) void attn_k(const float* __restrict__ qkv, float* __restrict__ out,
                                              const int* __restrict__ cntp, int S)
{
    extern __shared__ float lds[];
    float* Kl = lds;
    float* Vl = lds + (size_t)S * 65;
    int h = blockIdx.x, b = blockIdx.y;
    int nk = MASKED ? cntp[b] : S;
    const float* base = qkv + ((size_t)b * S) * 2304 + h * 64;

    for (int idx = threadIdx.x; idx < S * 16; idx += 256) {
        int r = idx >> 4, d4 = (idx & 15) << 2;
        const float* rp = base + (size_t)r * 2304;
        float4 kv = *(const float4*)(rp + 768 + d4);
        float4 vv = *(const float4*)(rp + 1536 + d4);
        Kl[r * 65 + d4 + 0] = kv.x; Kl[r * 65 + d4 + 1] = kv.y;
        Kl[r * 65 + d4 + 2] = kv.z; Kl[r * 65 + d4 + 3] = kv.w;
        Vl[r * 65 + d4 + 0] = vv.x; Vl[r * 65 + d4 + 1] = vv.y;
        Vl[r * 65 + d4 + 2] = vv.z; Vl[r * 65 + d4 + 3] = vv.w;
    }
    __syncthreads();

    int wv = threadIdx.x >> 6, ln = threadIdx.x & 63;
    int j0 = ln, j1 = ln + 64, j2 = ln + 128, j3 = ln + 192;
    int c0 = min(j0, S - 1), c1 = min(j1, S - 1), c2 = min(j2, S - 1), c3 = min(j3, S - 1);
    bool m0 = j0 < nk, m1 = j1 < nk, m2 = j2 < nk, m3 = j3 < nk;
    const float NEGBIG = -3.0e38f;

    for (int row = wv; row < S; row += 4) {
        size_t ob = ((size_t)b * S + row) * 768 + (size_t)h * 64 + ln;
        if (row < nk) {
            float qv = base[(size_t)row * 2304 + ln];
            float s0 = 0.f, s1 = 0.f, s2 = 0.f, s3 = 0.f;
            for (int d = 0; d < 64; ++d) {
                float qd = __shfl(qv, d);
                s0 = fmaf(qd, Kl[c0 * 65 + d], s0);
                s1 = fmaf(qd, Kl[c1 * 65 + d], s1);
                s2 = fmaf(qd, Kl[c2 * 65 + d], s2);
                s3 = fmaf(qd, Kl[c3 * 65 + d], s3);
            }
            s0 = m0 ? s0 * 0.125f : NEGBIG;
            s1 = m1 ? s1 * 0.125f : NEGBIG;
            s2 = m2 ? s2 * 0.125f : NEGBIG;
            s3 = m3 ? s3 * 0.125f : NEGBIG;
            float mx = fmaxf(fmaxf(s0, s1), fmaxf(s2, s3));
#pragma unroll
            for (int o = 32; o; o >>= 1) mx = fmaxf(mx, __shfl_xor(mx, o));
            float p0 = m0 ? expf(s0 - mx) : 0.f;
            float p1 = m1 ? expf(s1 - mx) : 0.f;
            float p2 = m2 ? expf(s2 - mx) : 0.f;
            float p3 = m3 ? expf(s3 - mx) : 0.f;
            float sum = p0 + p1 + p2 + p3;
#pragma unroll
            for (int o = 32; o; o >>= 1) sum += __shfl_xor(sum, o);
            float inv = 1.f / sum;

            float ov = 0.f;
#pragma unroll
            for (int seg = 0; seg < 4; ++seg) {
                float ps = (seg == 0) ? p0 : (seg == 1) ? p1 : (seg == 2) ? p2 : p3;
                int jend = nk - (seg << 6);
                if (jend > 64) jend = 64;
                for (int jj = 0; jj < jend; ++jj) {
                    float pj = __shfl(ps, jj);
                    ov = fmaf(pj, Vl[((seg << 6) + jj) * 65 + ln], ov);
                }
            }
            out[ob] = ov * inv;
        } else {
            out[ob] = 0.f;
        }
    }
}

// ---------------------------------------------------------------- token score (||x||^2, monotone in norm)
__global__ __launch_bounds__(256) void normsq_k(const float* __restrict__ x, float* __restrict__ norms)
{
    const float* xr = x + (size_t)blockIdx.x * 768;
    int t = threadIdx.x;
    float v0 = xr[t], v1 = xr[t + 256], v2 = xr[t + 512];
    float ss = v0 * v0 + v1 * v1 + v2 * v2;
#pragma unroll
    for (int o = 32; o; o >>= 1) ss += __shfl_xor(ss, o);
    __shared__ float r1[4];
    if ((t & 63) == 0) r1[t >> 6] = ss;
    __syncthreads();
    if (t == 0) norms[blockIdx.x] = r1[0] + r1[1] + r1[2] + r1[3];
}

// top-98 by (value desc, index asc) + CLS; emit kept indices in original order.
__global__ __launch_bounds__(256) void topk_k(const float* __restrict__ norms,
                                              int* __restrict__ idxmap, int* __restrict__ cnt)
{
    int b = blockIdx.x, t = threadIdx.x;
    __shared__ float n[NTOK];
    __shared__ unsigned char kp[NTOK];
    if (t < NTOK) n[t] = norms[b * NTOK + t];
    __syncthreads();
    if (t < NTOK) {
        float me = n[t];
        int rank = 0;
        for (int j = 0; j < NTOK; j++) rank += (n[j] > me) || (n[j] == me && j < t);
        kp[t] = (rank < 98) || (t == 0);
    }
    __syncthreads();
    if (t == 0) {
        int c = 0;
        for (int s = 0; s < NTOK; s++) if (kp[s]) idxmap[b * SL + c++] = s;
        cnt[b] = c;
        for (int j = c; j < SL; j++) idxmap[b * SL + j] = 0;
    }
}

__global__ __launch_bounds__(256) void gather_k(const float* __restrict__ x, const int* __restrict__ idxmap,
                                                const int* __restrict__ cnt, float* __restrict__ xl)
{
    int j = blockIdx.x, b = blockIdx.y;
    size_t dst = ((size_t)b * SL + j) * 768;
    if (j < cnt[b]) {
        int s = idxmap[b * SL + j];
        size_t src = ((size_t)b * NTOK + s) * 768;
        for (int d = threadIdx.x; d < 768; d += 256) xl[dst + d] = x[src + d];
    } else {
        for (int d = threadIdx.x; d < 768; d += 256) xl[dst + d] = 0.f;
    }
}

// ---------------------------------------------------------------- launch
extern "C" void kernel_launch(void* const* d_in, const int* in_sizes, int n_in,
                              void* d_out, int out_size, void* d_ws, size_t ws_size,
                              hipStream_t stream)
{
    const float* images  = (const float*)d_in[0];
    const float* patch_w = (const float*)d_in[1];
    const float* patch_b = (const float*)d_in[2];
    const float* cls_tok = (const float*)d_in[3];
    const float* pos_emb = (const float*)d_in[4];
    const float* ln1_g   = (const float*)d_in[5];
    const float* ln1_b   = (const float*)d_in[6];
    const float* qkv_w   = (const float*)d_in[7];
    const float* qkv_b   = (const float*)d_in[8];
    const float* proj_w  = (const float*)d_in[9];
    const float* proj_b  = (const float*)d_in[10];
    const float* ln2_g   = (const float*)d_in[11];
    const float* ln2_b   = (const float*)d_in[12];
    const float* fc1_w   = (const float*)d_in[13];
    const float* fc1_b   = (const float*)d_in[14];
    const float* fc2_w   = (const float*)d_in[15];
    const float* fc2_b   = (const float*)d_in[16];
    const float* norm_g  = (const float*)d_in[17];
    const float* norm_b  = (const float*)d_in[18];
    const float* head_w  = (const float*)d_in[19];
    const float* head_b  = (const float*)d_in[20];
    float* outp = (float*)d_out;

    // workspace layout (floats). total ~271.5 MB.
    float* x    = (float*)d_ws;            // 64*197*768
    float* hb   = x   + 9682944;           // 64*197*768
    float* ao   = hb  + 9682944;           // 64*197*768
    float* big  = ao  + 9682944;           // 64*197*3072 (also patches / qkv)
    float* norms = big + 38731776;         // 12608
    float* clsb  = norms + 12608;          // 64*768
    int* idxmap  = (int*)(clsb + 49152);   // 64*99
    int* cnt     = idxmap + NB * SL;       // 64

    (void)hipFuncSetAttribute(reinterpret_cast<const void*>(attn_k<false>),
                              hipFuncAttributeMaxDynamicSharedMemorySize, NTOK * 65 * 2 * 4);
    (void)hipFuncSetAttribute(reinterpret_cast<const void*>(attn_k<true>),
                              hipFuncAttributeMaxDynamicSharedMemorySize, SL * 65 * 2 * 4);

    // patch embed
    patch_extract_k<<<dim3(196, NB), 256, 0, stream>>>(images, big);
    gemm_k<0, false><<<dim3(6, 98), 256, 0, stream>>>(big, patch_w, patch_b, nullptr, ao, 12544, 768, 768);
    assemble_k<<<dim3(NTOK, NB), 256, 0, stream>>>(ao, cls_tok, pos_emb, x);

    const int M1 = NB * NTOK;   // 12608
    for (int i = 0; i < 4; i++) {
        ln_k<<<M1, 256, 0, stream>>>(x, hb, ln1_g + (size_t)i * 768, ln1_b + (size_t)i * 768, 768, 768);
        gemm_k<0, false><<<dim3(18, (M1 + 127) / 128), 256, 0, stream>>>(
            hb, qkv_w + (size_t)i * 2304 * 768, qkv_b + (size_t)i * 2304, nullptr, big, M1, 2304, 768);
        attn_k<false><<<dim3(NHEAD, NB), 256, NTOK * 65 * 2 * 4, stream>>>(big, ao, nullptr, NTOK);
        gemm_k<0, true><<<dim3(6, (M1 + 127) / 128), 256, 0, stream>>>(
            ao, proj_w + (size_t)i * 768 * 768, proj_b + (size_t)i * 768, x, x, M1, 768, 768);
        ln_k<<<M1, 256, 0, stream>>>(x, hb, ln2_g + (size_t)i * 768, ln2_b + (size_t)i * 768, 768, 768);
        gemm_k<1, false><<<dim3(24, (M1 + 127) / 128), 256, 0, stream>>>(
            hb, fc1_w + (size_t)i * 3072 * 768, fc1_b + (size_t)i * 3072, nullptr, big, M1, 3072, 768);
        gemm_k<0, true><<<dim3(6, (M1 + 127) / 128), 256, 0, stream>>>(
            big, fc2_w + (size_t)i * 768 * 3072, fc2_b + (size_t)i * 768, x, x, M1, 768, 3072);
    }

    // prune + compact
    normsq_k<<<M1, 256, 0, stream>>>(x, norms);
    topk_k<<<NB, 256, 0, stream>>>(norms, idxmap, cnt);
    gather_k<<<dim3(SL, NB), 256, 0, stream>>>(x, idxmap, cnt, hb);

    float* xl = hb;   // late residual stream [64*99, 768]
    float* hl = x;    // late LN buffer
    const int M2 = NB * SL;     // 6336
    for (int i = 4; i < 12; i++) {
        ln_k<<<M2, 256, 0, stream>>>(xl, hl, ln1_g + (size_t)i * 768, ln1_b + (size_t)i * 768, 768, 768);
        gemm_k<0, false><<<dim3(18, (M2 + 127) / 128), 256, 0, stream>>>(
            hl, qkv_w + (size_t)i * 2304 * 768, qkv_b + (size_t)i * 2304, nullptr, big, M2, 2304, 768);
        attn_k<true><<<dim3(NHEAD, NB), 256, SL * 65 * 2 * 4, stream>>>(big, ao, cnt, SL);
        gemm_k<0, true><<<dim3(6, (M2 + 127) / 128), 256, 0, stream>>>(
            ao, proj_w + (size_t)i * 768 * 768, proj_b + (size_t)i * 768, xl, xl, M2, 768, 768);
        ln_k<<<M2, 256, 0, stream>>>(xl, hl, ln2_g + (size_t)i * 768, ln2_b + (size_t)i * 768, 768, 768);
        gemm_k<1, false><<<dim3(24, (M2 + 127) / 128), 256, 0, stream>>>(
            hl, fc1_w + (size_t)i * 3072 * 768, fc1_b + (size_t)i * 3072, nullptr, big, M2, 3072, 768);
        gemm_k<0, true><<<dim3(6, (M2 + 127) / 128), 256, 0, stream>>>(
            big, fc2_w + (size_t)i * 768 * 3072, fc2_b + (size_t)i * 768, xl, xl, M2, 768, 3072);
    }

    // final: LN(CLS) + head
    ln_k<<<NB, 256, 0, stream>>>(xl, clsb, norm_g, norm_b, (size_t)SL * 768, 768);
    gemm_k<0, false><<<dim3(8, 1), 256, 0, stream>>>(clsb, head_w, head_b, nullptr, outp, 64, 1000, 768);
}

// Round 2
// 6806.783 us; speedup vs baseline: 4.5553x; 4.5553x over previous
//
#include <hip/hip_runtime.h>
#include <cstdint>
#include <cstddef>

// ViT-B/16 + token pruning. Round 2: bf16 MFMA GEMMs + fused MFMA attention.
// Pre-prune path (patch embed + blocks 0-3) uses 2-term bf16 split (3 MFMAs)
// for ~1.5e-5 relative accuracy so the top-98 token selection matches the
// fp32 reference. Post-prune path (blocks 4-11, head) is plain bf16.

#define NTOK 197
#define NB 64
#define NHEAD 12
#define SL 99

typedef __attribute__((ext_vector_type(8))) short short8;
typedef __attribute__((ext_vector_type(4))) float f32x4;
typedef __attribute__((ext_vector_type(4))) unsigned short us4;

#define DEV static __device__ __forceinline__

DEV unsigned short f2bf(float f) {
    union { float f; unsigned int u; } v; v.f = f;
    unsigned int r = (v.u + 0x7FFFu + ((v.u >> 16) & 1u)) >> 16;
    return (unsigned short)r;
}
DEV float bf2f(unsigned short h) {
    union { float f; unsigned int u; } v; v.u = ((unsigned int)h) << 16;
    return v.f;
}
DEV void gload16(const void* g, void* l) {
    __builtin_amdgcn_global_load_lds((const __attribute__((address_space(1))) unsigned int*)g,
                                     (__attribute__((address_space(3))) unsigned int*)l, 16, 0, 0);
}

// ---------------------------------------------------------------- fp32->bf16 weight conversion
// per-layer fused: [qkv 1769472 | proj 589824 | fc1 2359296 | fc2 2359296] = 7077888 elems
template<int SP>
__global__ __launch_bounds__(256) void cvt_layer_k(const float* __restrict__ qw,
                                                   const float* __restrict__ pw,
                                                   const float* __restrict__ f1,
                                                   const float* __restrict__ f2,
                                                   unsigned short* __restrict__ dh,
                                                   unsigned short* __restrict__ dl)
{
    size_t t = (size_t)blockIdx.x * 256 + threadIdx.x;   // < 1769472
    size_t e = t * 4;
    const float* src; size_t loc;
    if (e < 1769472)      { src = qw; loc = e; }
    else if (e < 2359296) { src = pw; loc = e - 1769472; }
    else if (e < 4718592) { src = f1; loc = e - 2359296; }
    else                  { src = f2; loc = e - 4718592; }
    float4 v = *(const float4*)(src + loc);
    us4 hi; hi.x = f2bf(v.x); hi.y = f2bf(v.y); hi.z = f2bf(v.z); hi.w = f2bf(v.w);
    *(us4*)(dh + e) = hi;
    if (SP) {
        us4 lo;
        lo.x = f2bf(v.x - bf2f(hi.x)); lo.y = f2bf(v.y - bf2f(hi.y));
        lo.z = f2bf(v.z - bf2f(hi.z)); lo.w = f2bf(v.w - bf2f(hi.w));
        *(us4*)(dl + e) = lo;
    }
}

template<int SP>
__global__ __launch_bounds__(256) void cvt_simple_k(const float* __restrict__ src,
                                                    unsigned short* __restrict__ dh,
                                                    unsigned short* __restrict__ dl, int n4)
{
    int t = blockIdx.x * 256 + threadIdx.x;
    if (t >= n4) return;
    size_t e = (size_t)t * 4;
    float4 v = *(const float4*)(src + e);
    us4 hi; hi.x = f2bf(v.x); hi.y = f2bf(v.y); hi.z = f2bf(v.z); hi.w = f2bf(v.w);
    *(us4*)(dh + e) = hi;
    if (SP) {
        us4 lo;
        lo.x = f2bf(v.x - bf2f(hi.x)); lo.y = f2bf(v.y - bf2f(hi.y));
        lo.z = f2bf(v.z - bf2f(hi.z)); lo.w = f2bf(v.w - bf2f(hi.w));
        *(us4*)(dl + e) = lo;
    }
}

// ---------------------------------------------------------------- patch extract (fp32 -> split bf16)
__global__ __launch_bounds__(256) void patch_extract2_k(const float* __restrict__ img,
                                                        unsigned short* __restrict__ ph,
                                                        unsigned short* __restrict__ pl)
{
    int pi = blockIdx.x, b = blockIdx.y;
    int gy = pi / 14, gx = pi % 14;
    size_t obase = ((size_t)b * 196 + pi) * 768;
    for (int f = threadIdx.x; f < 768; f += 256) {
        int c = f >> 8, py = (f >> 4) & 15, px = f & 15;
        float v = img[(((size_t)b * 3 + c) * 224 + gy * 16 + py) * 224 + gx * 16 + px];
        unsigned short hi = f2bf(v);
        ph[obase + f] = hi;
        pl[obase + f] = f2bf(v - bf2f(hi));
    }
}

__global__ __launch_bounds__(256) void assemble_k(const float* __restrict__ emb,
                                                  const float* __restrict__ cls,
                                                  const float* __restrict__ pos,
                                                  float* __restrict__ x)
{
    int s = blockIdx.x, b = blockIdx.y;
    size_t xo = ((size_t)b * NTOK + s) * 768;
    for (int d = threadIdx.x; d < 768; d += 256) {
        float v = (s == 0) ? cls[d] : emb[((size_t)b * 196 + (s - 1)) * 768 + d];
        x[xo + d] = v + pos[(size_t)s * 768 + d];
    }
}

// ---------------------------------------------------------------- layernorm fp32 in -> bf16 out (OS=2: hi/lo split)
template<int OS>
__global__ __launch_bounds__(256) void ln2_k(const float* __restrict__ in,
                                             unsigned short* __restrict__ outh,
                                             unsigned short* __restrict__ outl,
                                             const float* __restrict__ g,
                                             const float* __restrict__ bt, size_t ldin)
{
    const float* xr = in + (size_t)blockIdx.x * ldin;
    size_t ob = (size_t)blockIdx.x * 768;
    int t = threadIdx.x;
    float v0 = xr[t], v1 = xr[t + 256], v2 = xr[t + 512];
    float s = v0 + v1 + v2;
#pragma unroll
    for (int o = 32; o; o >>= 1) s += __shfl_xor(s, o);
    __shared__ float r1[4], r2[4];
    int wv = t >> 6, ln = t & 63;
    if (ln == 0) r1[wv] = s;
    __syncthreads();
    float mean = (r1[0] + r1[1] + r1[2] + r1[3]) * (1.f / 768.f);
    float d0 = v0 - mean, d1 = v1 - mean, d2 = v2 - mean;
    float ss = d0 * d0 + d1 * d1 + d2 * d2;
#pragma unroll
    for (int o = 32; o; o >>= 1) ss += __shfl_xor(ss, o);
    if (ln == 0) r2[wv] = ss;
    __syncthreads();
    float inv = rsqrtf((r2[0] + r2[1] + r2[2] + r2[3]) * (1.f / 768.f) + 1e-6f);
    float y0 = d0 * inv * g[t] + bt[t];
    float y1 = d1 * inv * g[t + 256] + bt[t + 256];
    float y2 = d2 * inv * g[t + 512] + bt[t + 512];
    unsigned short h0 = f2bf(y0), h1 = f2bf(y1), h2 = f2bf(y2);
    outh[ob + t] = h0; outh[ob + t + 256] = h1; outh[ob + t + 512] = h2;
    if (OS == 2) {
        outl[ob + t] = f2bf(y0 - bf2f(h0));
        outl[ob + t + 256] = f2bf(y1 - bf2f(h1));
        outl[ob + t + 512] = f2bf(y2 - bf2f(h2));
    }
}

// ---------------------------------------------------------------- MFMA GEMM: C = op(A@W^T + bias [+res])
// A[M,K], W[N,K] bf16 (optionally split hi/lo). 128x128 tile, BK=32, 4 waves.
// SPLIT: 3-MFMA split accumulation. EPI: 0 none, 1 GELU, 2 +res. OS: 0 fp32, 1 bf16, 2 bf16 split.
template<int SPLIT, int EPI, int OS>
__global__ __launch_bounds__(256) void mgemm_k(const unsigned short* __restrict__ Ah,
                                               const unsigned short* __restrict__ Al,
                                               const unsigned short* __restrict__ Wh,
                                               const unsigned short* __restrict__ Wl,
                                               const float* __restrict__ bias,
                                               const float* __restrict__ res,
                                               unsigned short* __restrict__ Chi,
                                               unsigned short* __restrict__ Clo,
                                               float* __restrict__ Cf,
                                               int M, int N, int K)
{
    constexpr int NP = SPLIT ? 2 : 1;
    __shared__ unsigned short lds[NP * 2 * 4096];
    unsigned short* As = lds;
    unsigned short* Bs = lds + NP * 4096;

    const int tid = threadIdx.x;
    const int w = tid >> 6, lane = tid & 63;
    const int row0 = blockIdx.y * 128, col0 = blockIdx.x * 128;
    const int wr = w >> 1, wc = w & 1;
    const int srow = lane >> 2;
    const int schunk = (lane & 3) * 8;
    const int fr = lane & 15, fq = lane >> 4;

    f32x4 acc[4][4];
#pragma unroll
    for (int m = 0; m < 4; m++)
#pragma unroll
        for (int n = 0; n < 4; n++) acc[m][n] = (f32x4)0.f;

    for (int k0 = 0; k0 < K; k0 += 32) {
#pragma unroll
        for (int p = 0; p < NP; p++) {
            const unsigned short* Ap = p ? Al : Ah;
            const unsigned short* Wp = p ? Wl : Wh;
#pragma unroll
            for (int i = 0; i < 2; i++) {
                int r = i * 64 + w * 16 + srow;
                gload16(Ap + (size_t)(row0 + r) * K + k0 + schunk,
                        As + p * 4096 + i * 2048 + w * 512);
                gload16(Wp + (size_t)(col0 + r) * K + k0 + schunk,
                        Bs + p * 4096 + i * 2048 + w * 512);
            }
        }
        __syncthreads();
        short8 a[NP][4], b[NP][4];
#pragma unroll
        for (int p = 0; p < NP; p++)
#pragma unroll
            for (int m = 0; m < 4; m++)
                a[p][m] = *(const short8*)(As + p * 4096 + (wr * 64 + m * 16 + fr) * 32 + fq * 8);
#pragma unroll
        for (int p = 0; p < NP; p++)
#pragma unroll
            for (int n = 0; n < 4; n++)
                b[p][n] = *(const short8*)(Bs + p * 4096 + (wc * 64 + n * 16 + fr) * 32 + fq * 8);
#pragma unroll
        for (int m = 0; m < 4; m++)
#pragma unroll
            for (int n = 0; n < 4; n++) {
                acc[m][n] = __builtin_amdgcn_mfma_f32_16x16x32_bf16(a[0][m], b[0][n], acc[m][n], 0, 0, 0);
                if (SPLIT) {
                    acc[m][n] = __builtin_amdgcn_mfma_f32_16x16x32_bf16(a[0][m], b[1][n], acc[m][n], 0, 0, 0);
                    acc[m][n] = __builtin_amdgcn_mfma_f32_16x16x32_bf16(a[1][m], b[0][n], acc[m][n], 0, 0, 0);
                }
            }
        __syncthreads();
    }

#pragma unroll
    for (int m = 0; m < 4; m++) {
#pragma unroll
        for (int n = 0; n < 4; n++) {
            int col = col0 + wc * 64 + n * 16 + fr;
#pragma unroll
            for (int r = 0; r < 4; r++) {
                int row = row0 + wr * 64 + m * 16 + fq * 4 + r;
                if (row < M && col < N) {
                    float v = acc[m][n][r] + bias[col];
                    size_t o = (size_t)row * N + col;
                    if (EPI == 2) v += res[o];
                    if (EPI == 1) v = 0.5f * v * (1.f + erff(v * 0.70710678118654752f));
                    if (OS == 0) Cf[o] = v;
                    else if (OS == 1) Chi[o] = f2bf(v);
                    else { unsigned short hh = f2bf(v); Chi[o] = hh; Clo[o] = f2bf(v - bf2f(hh)); }
                }
            }
        }
    }
}

// ---------------------------------------------------------------- fused MFMA attention
// qkv rows [B*S, 2304]: q at h*64, k at 768+h*64, v at 1536+h*64 (bf16 planes).
// One block (4 waves) per (b,h). Each wave handles q-tiles of 16 rows.
// Keys j >= nk masked (p=0). V transposed into LDS; P staged per-wave in LDS.
template<int SPLIT, int S, int KT, int PVKT, int PSTR>
__global__ __launch_bounds__(256) void attn2_k(const unsigned short* __restrict__ qh,
                                               const unsigned short* __restrict__ ql,
                                               unsigned short* __restrict__ oh,
                                               unsigned short* __restrict__ ol,
                                               const int* __restrict__ cntp)
{
    constexpr int NP = SPLIT ? 2 : 1;
    constexpr int PVK = PVKT * 32;
    constexpr int QT = (S + 15) / 16;
    extern __shared__ unsigned short sh[];
    unsigned short* VT = sh;                      // NP * 64 * PSTR   ([plane][d][j])
    unsigned short* PL = sh + NP * 64 * PSTR;     // 4 * NP * 16 * PSTR

    const int h = blockIdx.x, b = blockIdx.y;
    const int tid = threadIdx.x, w = tid >> 6, lane = tid & 63;
    const int nk = cntp ? cntp[b] : S;
    const size_t qbase = (size_t)b * S * 2304 + (size_t)h * 64;
    const int fr = lane & 15, fq = lane >> 4;

    // stage V^T
    for (int j0 = 0; j0 < S; j0 += 32) {
        int j = j0 + (tid >> 3);
        int d8 = (tid & 7) * 8;
        if (j < S) {
            size_t src = qbase + (size_t)j * 2304 + 1536 + d8;
#pragma unroll
            for (int p = 0; p < NP; p++) {
                const unsigned short* qp = p ? ql : qh;
                short8 v = *(const short8*)(qp + src);
#pragma unroll
                for (int e = 0; e < 8; e++)
                    VT[p * 64 * PSTR + (d8 + e) * PSTR + j] = ((unsigned short*)&v)[e];
            }
        }
    }
    for (int idx = tid; idx < 64 * (PVK - S); idx += 256) {
        int d = idx / (PVK - S), j = S + idx % (PVK - S);
#pragma unroll
        for (int p = 0; p < NP; p++) VT[p * 64 * PSTR + d * PSTR + j] = 0;
    }
    {   // zero P pad cols [16*KT, PVK) once (never rewritten)
        unsigned short* Pw = PL + w * NP * 16 * PSTR;
        for (int idx = lane; idx < 16 * (PVK - 16 * KT); idx += 64) {
            int rr = idx / (PVK - 16 * KT), cc = 16 * KT + idx % (PVK - 16 * KT);
#pragma unroll
            for (int p = 0; p < NP; p++) Pw[p * 16 * PSTR + rr * PSTR + cc] = 0;
        }
    }
    __syncthreads();

    for (int qt = w; qt < QT; qt += 4) {
        int qr = qt * 16 + fr; int qrc = qr < S ? qr : S - 1;
        const size_t qrow = qbase + (size_t)qrc * 2304;
        short8 qf0[2], qf1[2];
#pragma unroll
        for (int ks = 0; ks < 2; ks++) {
            qf0[ks] = *(const short8*)(qh + qrow + ks * 32 + fq * 8);
            if (SPLIT) qf1[ks] = *(const short8*)(ql + qrow + ks * 32 + fq * 8);
        }
        // QK^T: acc per key-tile; C layout: col(key)=fr, row(q)=fq*4+reg
        f32x4 sc[KT];
#pragma unroll
        for (int kt = 0; kt < KT; kt++) {
            int ky = kt * 16 + fr; int kyc = ky < S ? ky : S - 1;
            const size_t krow = qbase + (size_t)kyc * 2304 + 768;
            f32x4 acc = (f32x4)0.f;
#pragma unroll
            for (int ks = 0; ks < 2; ks++) {
                short8 kh = *(const short8*)(qh + krow + ks * 32 + fq * 8);
                acc = __builtin_amdgcn_mfma_f32_16x16x32_bf16(qf0[ks], kh, acc, 0, 0, 0);
                if (SPLIT) {
                    short8 kl = *(const short8*)(ql + krow + ks * 32 + fq * 8);
                    acc = __builtin_amdgcn_mfma_f32_16x16x32_bf16(qf0[ks], kl, acc, 0, 0, 0);
                    acc = __builtin_amdgcn_mfma_f32_16x16x32_bf16(qf1[ks], kh, acc, 0, 0, 0);
                }
            }
            sc[kt] = acc;
        }
        // softmax (fp32, rowwise across fr-group and kt)
        float mx[4] = {-3e38f, -3e38f, -3e38f, -3e38f};
#pragma unroll
        for (int kt = 0; kt < KT; kt++) {
            bool valid = (kt * 16 + fr) < nk;
#pragma unroll
            for (int r = 0; r < 4; r++) {
                float s = sc[kt][r] * 0.125f;
                sc[kt][r] = s;
                if (valid) mx[r] = fmaxf(mx[r], s);
            }
        }
#pragma unroll
        for (int off = 1; off < 16; off <<= 1)
#pragma unroll
            for (int r = 0; r < 4; r++) mx[r] = fmaxf(mx[r], __shfl_xor(mx[r], off));
        float sum[4] = {0.f, 0.f, 0.f, 0.f};
#pragma unroll
        for (int kt = 0; kt < KT; kt++) {
            bool valid = (kt * 16 + fr) < nk;
#pragma unroll
            for (int r = 0; r < 4; r++) {
                float p = 0.f;
                if (valid) p = SPLIT ? expf(sc[kt][r] - mx[r]) : __expf(sc[kt][r] - mx[r]);
                sc[kt][r] = p;
                sum[r] += p;
            }
        }
#pragma unroll
        for (int off = 1; off < 16; off <<= 1)
#pragma unroll
            for (int r = 0; r < 4; r++) sum[r] += __shfl_xor(sum[r], off);
        float inv[4];
#pragma unroll
        for (int r = 0; r < 4; r++) inv[r] = 1.f / sum[r];
        // stage P (per-wave, row=q, col=key)
        unsigned short* Pw = PL + w * NP * 16 * PSTR;
#pragma unroll
        for (int kt = 0; kt < KT; kt++) {
#pragma unroll
            for (int r = 0; r < 4; r++) {
                float p = sc[kt][r] * inv[r];
                unsigned short hh = f2bf(p);
                Pw[(fq * 4 + r) * PSTR + kt * 16 + fr] = hh;
                if (SPLIT) Pw[16 * PSTR + (fq * 4 + r) * PSTR + kt * 16 + fr] = f2bf(p - bf2f(hh));
            }
        }
        // PV
        f32x4 o[4];
#pragma unroll
        for (int n = 0; n < 4; n++) o[n] = (f32x4)0.f;
#pragma unroll
        for (int ks = 0; ks < PVKT; ks++) {
            short8 pa = *(const short8*)(Pw + fr * PSTR + ks * 32 + fq * 8);
            short8 pl2;
            if (SPLIT) pl2 = *(const short8*)(Pw + 16 * PSTR + fr * PSTR + ks * 32 + fq * 8);
#pragma unroll
            for (int n = 0; n < 4; n++) {
                short8 vb = *(const short8*)(VT + (n * 16 + fr) * PSTR + ks * 32 + fq * 8);
                o[n] = __builtin_amdgcn_mfma_f32_16x16x32_bf16(pa, vb, o[n], 0, 0, 0);
                if (SPLIT) {
                    short8 vl = *(const short8*)(VT + 64 * PSTR + (n * 16 + fr) * PSTR + ks * 32 + fq * 8);
                    o[n] = __builtin_amdgcn_mfma_f32_16x16x32_bf16(pa, vl, o[n], 0, 0, 0);
                    o[n] = __builtin_amdgcn_mfma_f32_16x16x32_bf16(pl2, vb, o[n], 0, 0, 0);
                }
            }
        }
        // store
#pragma unroll
        for (int n = 0; n < 4; n++) {
#pragma unroll
            for (int r = 0; r < 4; r++) {
                int row = qt * 16 + fq * 4 + r;
                if (row < S) {
                    size_t oidx = ((size_t)b * S + row) * 768 + (size_t)h * 64 + n * 16 + fr;
                    float vv = o[n][r];
                    unsigned short hh = f2bf(vv);
                    oh[oidx] = hh;
                    if (SPLIT) ol[oidx] = f2bf(vv - bf2f(hh));
                }
            }
        }
    }
}

// ---------------------------------------------------------------- prune machinery (fp32, unchanged)
__global__ __launch_bounds__(256) void normsq_k(const float* __restrict__ x, float* __restrict__ norms)
{
    const float* xr = x + (size_t)blockIdx.x * 768;
    int t = threadIdx.x;
    float v0 = xr[t], v1 = xr[t + 256], v2 = xr[t + 512];
    float ss = v0 * v0 + v1 * v1 + v2 * v2;
#pragma unroll
    for (int o = 32; o; o >>= 1) ss += __shfl_xor(ss, o);
    __shared__ float r1[4];
    if ((t & 63) == 0) r1[t >> 6] = ss;
    __syncthreads();
    if (t == 0) norms[blockIdx.x] = r1[0] + r1[1] + r1[2] + r1[3];
}

__global__ __launch_bounds__(256) void topk_k(const float* __restrict__ norms,
                                              int* __restrict__ idxmap, int* __restrict__ cnt)
{
    int b = blockIdx.x, t = threadIdx.x;
    __shared__ float n[NTOK];
    __shared__ unsigned char kp[NTOK];
    if (t < NTOK) n[t] = norms[b * NTOK + t];
    __syncthreads();
    if (t < NTOK) {
        float me = n[t];
        int rank = 0;
        for (int j = 0; j < NTOK; j++) rank += (n[j] > me) || (n[j] == me && j < t);
        kp[t] = (rank < 98) || (t == 0);
    }
    __syncthreads();
    if (t == 0) {
        int c = 0;
        for (int s = 0; s < NTOK; s++) if (kp[s]) idxmap[b * SL + c++] = s;
        cnt[b] = c;
        for (int j = c; j < SL; j++) idxmap[b * SL + j] = 0;
    }
}

__global__ __launch_bounds__(256) void gather_k(const float* __restrict__ x, const int* __restrict__ idxmap,
                                                const int* __restrict__ cnt, float* __restrict__ xl)
{
    int j = blockIdx.x, b = blockIdx.y;
    size_t dst = ((size_t)b * SL + j) * 768;
    if (j < cnt[b]) {
        int s = idxmap[b * SL + j];
        size_t src = ((size_t)b * NTOK + s) * 768;
        for (int d = threadIdx.x; d < 768; d += 256) xl[dst + d] = x[src + d];
    } else {
        for (int d = threadIdx.x; d < 768; d += 256) xl[dst + d] = 0.f;
    }
}

// ---------------------------------------------------------------- launch
extern "C" void kernel_launch(void* const* d_in, const int* in_sizes, int n_in,
                              void* d_out, int out_size, void* d_ws, size_t ws_size,
                              hipStream_t stream)
{
    const float* images  = (const float*)d_in[0];
    const float* patch_w = (const float*)d_in[1];
    const float* patch_b = (const float*)d_in[2];
    const float* cls_tok = (const float*)d_in[3];
    const float* pos_emb = (const float*)d_in[4];
    const float* ln1_g   = (const float*)d_in[5];
    const float* ln1_b   = (const float*)d_in[6];
    const float* qkv_w   = (const float*)d_in[7];
    const float* qkv_b   = (const float*)d_in[8];
    const float* proj_w  = (const float*)d_in[9];
    const float* proj_b  = (const float*)d_in[10];
    const float* ln2_g   = (const float*)d_in[11];
    const float* ln2_b   = (const float*)d_in[12];
    const float* fc1_w   = (const float*)d_in[13];
    const float* fc1_b   = (const float*)d_in[14];
    const float* fc2_w   = (const float*)d_in[15];
    const float* fc2_b   = (const float*)d_in[16];
    const float* norm_g  = (const float*)d_in[17];
    const float* norm_b  = (const float*)d_in[18];
    const float* head_w  = (const float*)d_in[19];
    const float* head_b  = (const float*)d_in[20];
    float* outp = (float*)d_out;

    // -------- workspace layout (bytes) --------
    char* W = (char*)d_ws;
    float* x = (float*)W;                                       // 38,731,776
    unsigned short* hbh = (unsigned short*)(W + 38731776);      // 19,365,888 (LN out hi / attn-out hi)
    unsigned short* hbl = hbh + 9682944;                        // 19,365,888 (LN out lo / attn-out lo / late attn-out)
    char* R = W + 77463552;                                     // 154,927,104 shared region
    unsigned short* wbh = (unsigned short*)(W + 232390656);     // 14,155,776 (per-layer weights hi)
    unsigned short* wbl = wbh + 7077888;                        // 14,155,776 (lo)
    unsigned short* pwh = (unsigned short*)(W + 260702208);     // patch_w hi
    unsigned short* pwl = pwh + 589824;                         // patch_w lo
    unsigned short* hwb = (unsigned short*)(W + 263061504);     // head_w (1024x768, rows>=1000 garbage)
    float* norms = (float*)(W + 264634368);
    unsigned short* clsb = (unsigned short*)(W + 264684800);    // 128x768 bf16
    int* idxmap = (int*)(W + 264881408);
    int* cnt    = (int*)(W + 264906752);

    // region R aliases (non-overlapping in time):
    unsigned short* ph  = (unsigned short*)R;                   // patches hi [12544*768]
    unsigned short* plo = ph + 9633792;                         // patches lo
    float* emb = (float*)(R + 38535168);                        // [12544*768] fp32
    unsigned short* qkh = (unsigned short*)R;                   // qkv out hi [12608*2304]
    unsigned short* qkl = qkh + 29048832;                       // qkv out lo
    unsigned short* ffh = (unsigned short*)R;                   // fc1 out hi [12608*3072]
    unsigned short* ffl = ffh + 38731776;                       // fc1 out lo
    float* xl = (float*)(R + 41943040);                         // late residual [6336*768] fp32 (beyond late qkv/ffb use)

    const int LDS_EARLY = (2 * 64 * 232 + 4 * 2 * 16 * 232) * 2;   // 118,784
    const int LDS_LATE  = (1 * 64 * 136 + 4 * 1 * 16 * 136) * 2;   // 34,816
    (void)hipFuncSetAttribute(reinterpret_cast<const void*>(&attn2_k<1, 197, 13, 7, 232>),
                              hipFuncAttributeMaxDynamicSharedMemorySize, LDS_EARLY);
    (void)hipFuncSetAttribute(reinterpret_cast<const void*>(&attn2_k<0, 99, 7, 4, 136>),
                              hipFuncAttributeMaxDynamicSharedMemorySize, LDS_LATE);

    // ---- patch embed (split path) ----
    cvt_simple_k<1><<<576, 256, 0, stream>>>(patch_w, pwh, pwl, 147456);
    patch_extract2_k<<<dim3(196, NB), 256, 0, stream>>>(images, ph, plo);
    mgemm_k<1, 0, 0><<<dim3(6, 98), 256, 0, stream>>>(ph, plo, pwh, pwl, patch_b, nullptr,
                                                      nullptr, nullptr, emb, 12544, 768, 768);
    assemble_k<<<dim3(NTOK, NB), 256, 0, stream>>>(emb, cls_tok, pos_emb, x);

    const int M1 = NB * NTOK;   // 12608
    for (int i = 0; i < 4; i++) {
        cvt_layer_k<1><<<6912, 256, 0, stream>>>(qkv_w + (size_t)i * 1769472, proj_w + (size_t)i * 589824,
                                                 fc1_w + (size_t)i * 2359296, fc2_w + (size_t)i * 2359296,
                                                 wbh, wbl);
        ln2_k<2><<<M1, 256, 0, stream>>>(x, hbh, hbl, ln1_g + (size_t)i * 768, ln1_b + (size_t)i * 768, 768);
        mgemm_k<1, 0, 2><<<dim3(18, 99), 256, 0, stream>>>(hbh, hbl, wbh, wbl,
            qkv_b + (size_t)i * 2304, nullptr, qkh, qkl, nullptr, M1, 2304, 768);
        attn2_k<1, 197, 13, 7, 232><<<dim3(NHEAD, NB), 256, LDS_EARLY, stream>>>(qkh, qkl, hbh, hbl, nullptr);
        mgemm_k<1, 2, 0><<<dim3(6, 99), 256, 0, stream>>>(hbh, hbl, wbh + 1769472, wbl + 1769472,
            proj_b + (size_t)i * 768, x, nullptr, nullptr, x, M1, 768, 768);
        ln2_k<2><<<M1, 256, 0, stream>>>(x, hbh, hbl, ln2_g + (size_t)i * 768, ln2_b + (size_t)i * 768, 768);
        mgemm_k<1, 1, 2><<<dim3(24, 99), 256, 0, stream>>>(hbh, hbl, wbh + 2359296, wbl + 2359296,
            fc1_b + (size_t)i * 3072, nullptr, ffh, ffl, nullptr, M1, 3072, 768);
        mgemm_k<1, 2, 0><<<dim3(6, 99), 256, 0, stream>>>(ffh, ffl, wbh + 4718592, wbl + 4718592,
            fc2_b + (size_t)i * 768, x, nullptr, nullptr, x, M1, 768, 3072);
    }

    // ---- prune + compact ----
    normsq_k<<<M1, 256, 0, stream>>>(x, norms);
    topk_k<<<NB, 256, 0, stream>>>(norms, idxmap, cnt);
    gather_k<<<dim3(SL, NB), 256, 0, stream>>>(x, idxmap, cnt, xl);

    const int M2 = NB * SL;     // 6336
    for (int i = 4; i < 12; i++) {
        cvt_layer_k<0><<<6912, 256, 0, stream>>>(qkv_w + (size_t)i * 1769472, proj_w + (size_t)i * 589824,
                                                 fc1_w + (size_t)i * 2359296, fc2_w + (size_t)i * 2359296,
                                                 wbh, nullptr);
        ln2_k<1><<<M2, 256, 0, stream>>>(xl, hbh, nullptr, ln1_g + (size_t)i * 768, ln1_b + (size_t)i * 768, 768);
        mgemm_k<0, 0, 1><<<dim3(18, 50), 256, 0, stream>>>(hbh, nullptr, wbh, nullptr,
            qkv_b + (size_t)i * 2304, nullptr, qkh, nullptr, nullptr, M2, 2304, 768);
        attn2_k<0, 99, 7, 4, 136><<<dim3(NHEAD, NB), 256, LDS_LATE, stream>>>(qkh, nullptr, hbl, nullptr, cnt);
        mgemm_k<0, 2, 0><<<dim3(6, 50), 256, 0, stream>>>(hbl, nullptr, wbh + 1769472, nullptr,
            proj_b + (size_t)i * 768, xl, nullptr, nullptr, xl, M2, 768, 768);
        ln2_k<1><<<M2, 256, 0, stream>>>(xl, hbh, nullptr, ln2_g + (size_t)i * 768, ln2_b + (size_t)i * 768, 768);
        mgemm_k<0, 1, 1><<<dim3(24, 50), 256, 0, stream>>>(hbh, nullptr, wbh + 2359296, nullptr,
            fc1_b + (size_t)i * 3072, nullptr, ffh, nullptr, nullptr, M2, 3072, 768);
        mgemm_k<0, 2, 0><<<dim3(6, 50), 256, 0, stream>>>(ffh, nullptr, wbh + 4718592, nullptr,
            fc2_b + (size_t)i * 768, xl, nullptr, nullptr, xl, M2, 768, 3072);
    }

    // ---- final LN(CLS) + head ----
    ln2_k<1><<<NB, 256, 0, stream>>>(xl, clsb, nullptr, norm_g, norm_b, (size_t)SL * 768);
    cvt_simple_k<0><<<750, 256, 0, stream>>>(head_w, hwb, nullptr, 192000);
    mgemm_k<0, 0, 0><<<dim3(8, 1), 256, 0, stream>>>(clsb, nullptr, hwb, nullptr,
        head_b, nullptr, nullptr, nullptr, outp, 64, 1000, 768);
}

// Round 3
// 5955.375 us; speedup vs baseline: 5.2065x; 1.1430x over previous
//
#include <hip/hip_runtime.h>
#include <cstdint>
#include <cstddef>

// ViT-B/16 + token pruning. Round 3: dbuf-prefetch MFMA GEMM (1 barrier/K-step),
// XCD-aware grid mapping, LDS chunk-XOR swizzle. Split bf16 (3-MFMA) pre-prune,
// plain bf16 post-prune (norm-gap analysis: gaps ~1e-4 rel -> split required).

#define NTOK 197
#define NB 64
#define NHEAD 12
#define SL 99

typedef __attribute__((ext_vector_type(8))) short short8;
typedef __attribute__((ext_vector_type(4))) float f32x4;
typedef __attribute__((ext_vector_type(4))) unsigned short us4;

#define DEV static __device__ __forceinline__

DEV unsigned short f2bf(float f) {
    union { float f; unsigned int u; } v; v.f = f;
    unsigned int r = (v.u + 0x7FFFu + ((v.u >> 16) & 1u)) >> 16;
    return (unsigned short)r;
}
DEV float bf2f(unsigned short h) {
    union { float f; unsigned int u; } v; v.u = ((unsigned int)h) << 16;
    return v.f;
}
DEV void gload16(const void* g, void* l) {
    __builtin_amdgcn_global_load_lds((const __attribute__((address_space(1))) unsigned int*)g,
                                     (__attribute__((address_space(3))) unsigned int*)l, 16, 0, 0);
}

// ---------------------------------------------------------------- weight conversion
template<int SP>
__global__ __launch_bounds__(256) void cvt_layer_k(const float* __restrict__ qw,
                                                   const float* __restrict__ pw,
                                                   const float* __restrict__ f1,
                                                   const float* __restrict__ f2,
                                                   unsigned short* __restrict__ dh,
                                                   unsigned short* __restrict__ dl)
{
    size_t t = (size_t)blockIdx.x * 256 + threadIdx.x;
    size_t e = t * 4;
    const float* src; size_t loc;
    if (e < 1769472)      { src = qw; loc = e; }
    else if (e < 2359296) { src = pw; loc = e - 1769472; }
    else if (e < 4718592) { src = f1; loc = e - 2359296; }
    else                  { src = f2; loc = e - 4718592; }
    float4 v = *(const float4*)(src + loc);
    us4 hi; hi.x = f2bf(v.x); hi.y = f2bf(v.y); hi.z = f2bf(v.z); hi.w = f2bf(v.w);
    *(us4*)(dh + e) = hi;
    if (SP) {
        us4 lo;
        lo.x = f2bf(v.x - bf2f(hi.x)); lo.y = f2bf(v.y - bf2f(hi.y));
        lo.z = f2bf(v.z - bf2f(hi.z)); lo.w = f2bf(v.w - bf2f(hi.w));
        *(us4*)(dl + e) = lo;
    }
}

template<int SP>
__global__ __launch_bounds__(256) void cvt_simple_k(const float* __restrict__ src,
                                                    unsigned short* __restrict__ dh,
                                                    unsigned short* __restrict__ dl, int n4)
{
    int t = blockIdx.x * 256 + threadIdx.x;
    if (t >= n4) return;
    size_t e = (size_t)t * 4;
    float4 v = *(const float4*)(src + e);
    us4 hi; hi.x = f2bf(v.x); hi.y = f2bf(v.y); hi.z = f2bf(v.z); hi.w = f2bf(v.w);
    *(us4*)(dh + e) = hi;
    if (SP) {
        us4 lo;
        lo.x = f2bf(v.x - bf2f(hi.x)); lo.y = f2bf(v.y - bf2f(hi.y));
        lo.z = f2bf(v.z - bf2f(hi.z)); lo.w = f2bf(v.w - bf2f(hi.w));
        *(us4*)(dl + e) = lo;
    }
}

// ---------------------------------------------------------------- patch extract
__global__ __launch_bounds__(256) void patch_extract2_k(const float* __restrict__ img,
                                                        unsigned short* __restrict__ ph,
                                                        unsigned short* __restrict__ pl)
{
    int pi = blockIdx.x, b = blockIdx.y;
    int gy = pi / 14, gx = pi % 14;
    size_t obase = ((size_t)b * 196 + pi) * 768;
    for (int f = threadIdx.x; f < 768; f += 256) {
        int c = f >> 8, py = (f >> 4) & 15, px = f & 15;
        float v = img[(((size_t)b * 3 + c) * 224 + gy * 16 + py) * 224 + gx * 16 + px];
        unsigned short hi = f2bf(v);
        ph[obase + f] = hi;
        pl[obase + f] = f2bf(v - bf2f(hi));
    }
}

__global__ __launch_bounds__(256) void assemble_k(const float* __restrict__ emb,
                                                  const float* __restrict__ cls,
                                                  const float* __restrict__ pos,
                                                  float* __restrict__ x)
{
    int s = blockIdx.x, b = blockIdx.y;
    size_t xo = ((size_t)b * NTOK + s) * 768;
    for (int d = threadIdx.x; d < 768; d += 256) {
        float v = (s == 0) ? cls[d] : emb[((size_t)b * 196 + (s - 1)) * 768 + d];
        x[xo + d] = v + pos[(size_t)s * 768 + d];
    }
}

// ---------------------------------------------------------------- layernorm fp32 -> bf16 (OS=2: +lo plane)
template<int OS>
__global__ __launch_bounds__(256) void ln2_k(const float* __restrict__ in,
                                             unsigned short* __restrict__ outh,
                                             unsigned short* __restrict__ outl,
                                             const float* __restrict__ g,
                                             const float* __restrict__ bt, size_t ldin)
{
    const float* xr = in + (size_t)blockIdx.x * ldin;
    size_t ob = (size_t)blockIdx.x * 768;
    int t = threadIdx.x;
    float v0 = xr[t], v1 = xr[t + 256], v2 = xr[t + 512];
    float s = v0 + v1 + v2;
#pragma unroll
    for (int o = 32; o; o >>= 1) s += __shfl_xor(s, o);
    __shared__ float r1[4], r2[4];
    int wv = t >> 6, ln = t & 63;
    if (ln == 0) r1[wv] = s;
    __syncthreads();
    float mean = (r1[0] + r1[1] + r1[2] + r1[3]) * (1.f / 768.f);
    float d0 = v0 - mean, d1 = v1 - mean, d2 = v2 - mean;
    float ss = d0 * d0 + d1 * d1 + d2 * d2;
#pragma unroll
    for (int o = 32; o; o >>= 1) ss += __shfl_xor(ss, o);
    if (ln == 0) r2[wv] = ss;
    __syncthreads();
    float inv = rsqrtf((r2[0] + r2[1] + r2[2] + r2[3]) * (1.f / 768.f) + 1e-6f);
    float y0 = d0 * inv * g[t] + bt[t];
    float y1 = d1 * inv * g[t + 256] + bt[t + 256];
    float y2 = d2 * inv * g[t + 512] + bt[t + 512];
    unsigned short h0 = f2bf(y0), h1 = f2bf(y1), h2 = f2bf(y2);
    outh[ob + t] = h0; outh[ob + t + 256] = h1; outh[ob + t + 512] = h2;
    if (OS == 2) {
        outl[ob + t] = f2bf(y0 - bf2f(h0));
        outl[ob + t + 256] = f2bf(y1 - bf2f(h1));
        outl[ob + t + 512] = f2bf(y2 - bf2f(h2));
    }
}

// ---------------------------------------------------------------- MFMA GEMM, dbuf prefetch
// A[M,K], W[N,K] bf16 (split: hi/lo planes). 128x128 tile, BK=32, 4 waves.
// MAP: 0 linear (rt=bid%nR), 1 xcd rows-fastest, 2 xcd cols-fastest.
// One __syncthreads per K-step; prefetch next tile into other buffer.
// LDS chunk-XOR swizzle (chunk ^= (row>>1)&3), pre-swizzled on global source.
template<int SPLIT, int EPI, int OS, int MAP>
__global__ __launch_bounds__(256) void mgemm_k(const unsigned short* __restrict__ Ah,
                                               const unsigned short* __restrict__ Al,
                                               const unsigned short* __restrict__ Wh,
                                               const unsigned short* __restrict__ Wl,
                                               const float* __restrict__ bias,
                                               const float* __restrict__ res,
                                               unsigned short* __restrict__ Chi,
                                               unsigned short* __restrict__ Clo,
                                               float* __restrict__ Cf,
                                               int M, int N, int K, int nR, int nC, int nRmax)
{
    constexpr int NP = SPLIT ? 2 : 1;
    __shared__ unsigned short lds[2 * NP * 8192];   // [buf][A|B][plane][128 rows][32]

    int rt, ct;
    {
        int bid = blockIdx.x;
        if (MAP == 0) { rt = bid % nR; ct = bid / nR; }
        else {
            int x = bid & 7, u = bid >> 3, rl, c;
            if (MAP == 2) { c = u % nC; rl = u / nC; }
            else          { rl = u % nRmax; c = u / nRmax; }
            rt = x + 8 * rl; ct = c;
            if (rt >= nR) return;
        }
    }
    const int row0 = rt << 7, col0 = ct << 7;
    const int tid = threadIdx.x;
    const int w = tid >> 6, lane = tid & 63;
    const int wr = w >> 1, wc = w & 1;
    const int srow = lane >> 2;
    const int schunk = ((lane & 3) ^ ((srow >> 1) & 3)) << 3;  // pre-swizzled source chunk
    const int fr = lane & 15, fq = lane >> 4;
    const int rchunk = (fq ^ ((fr >> 1) & 3)) << 3;            // swizzled read chunk

    f32x4 acc[4][4];
#pragma unroll
    for (int m = 0; m < 4; m++)
#pragma unroll
        for (int n = 0; n < 4; n++) acc[m][n] = (f32x4)0.f;

    const int nk = K >> 5;

    auto stage = [&](int t, int bsel) {
        const int k0 = t << 5;
        unsigned short* Ad = lds + bsel * NP * 8192;
        unsigned short* Bd = Ad + NP * 4096;
#pragma unroll
        for (int p = 0; p < NP; p++) {
            const unsigned short* Ap = p ? Al : Ah;
            const unsigned short* Wp = p ? Wl : Wh;
#pragma unroll
            for (int i = 0; i < 2; i++) {
                int r = i * 64 + w * 16 + srow;
                int ga = row0 + r; if (ga > M - 1) ga = M - 1;
                int gb = col0 + r; if (gb > N - 1) gb = N - 1;
                gload16(Ap + (size_t)ga * K + k0 + schunk, Ad + p * 4096 + i * 2048 + w * 512);
                gload16(Wp + (size_t)gb * K + k0 + schunk, Bd + p * 4096 + i * 2048 + w * 512);
            }
        }
    };

    stage(0, 0);
    for (int t = 0; t < nk; ++t) {
        const int bsel = t & 1;
        __syncthreads();                       // drains prefetch (vmcnt0+lgkm0+barrier)
        const unsigned short* Ab = lds + bsel * NP * 8192;
        const unsigned short* Bb = Ab + NP * 4096;
        short8 a[NP][4], bb[NP][4];
#pragma unroll
        for (int p = 0; p < NP; p++)
#pragma unroll
            for (int m = 0; m < 4; m++)
                a[p][m] = *(const short8*)(Ab + p * 4096 + (wr * 64 + m * 16 + fr) * 32 + rchunk);
#pragma unroll
        for (int p = 0; p < NP; p++)
#pragma unroll
            for (int n = 0; n < 4; n++)
                bb[p][n] = *(const short8*)(Bb + p * 4096 + (wc * 64 + n * 16 + fr) * 32 + rchunk);
        if (t + 1 < nk) stage(t + 1, bsel ^ 1);
#pragma unroll
        for (int m = 0; m < 4; m++)
#pragma unroll
            for (int n = 0; n < 4; n++) {
                acc[m][n] = __builtin_amdgcn_mfma_f32_16x16x32_bf16(a[0][m], bb[0][n], acc[m][n], 0, 0, 0);
                if (SPLIT) {
                    acc[m][n] = __builtin_amdgcn_mfma_f32_16x16x32_bf16(a[0][m], bb[1][n], acc[m][n], 0, 0, 0);
                    acc[m][n] = __builtin_amdgcn_mfma_f32_16x16x32_bf16(a[1][m], bb[0][n], acc[m][n], 0, 0, 0);
                }
            }
    }

#pragma unroll
    for (int m = 0; m < 4; m++) {
#pragma unroll
        for (int n = 0; n < 4; n++) {
            int col = col0 + wc * 64 + n * 16 + fr;
#pragma unroll
            for (int r = 0; r < 4; r++) {
                int row = row0 + wr * 64 + m * 16 + fq * 4 + r;
                if (row < M && col < N) {
                    float v = acc[m][n][r] + bias[col];
                    size_t o = (size_t)row * N + col;
                    if (EPI == 2) v += res[o];
                    if (EPI == 1) v = 0.5f * v * (1.f + erff(v * 0.70710678118654752f));
                    if (OS == 0) Cf[o] = v;
                    else if (OS == 1) Chi[o] = f2bf(v);
                    else { unsigned short hh = f2bf(v); Chi[o] = hh; Clo[o] = f2bf(v - bf2f(hh)); }
                }
            }
        }
    }
}

// ---------------------------------------------------------------- fused MFMA attention (as round 2)
template<int SPLIT, int S, int KT, int PVKT, int PSTR>
__global__ __launch_bounds__(256) void attn2_k(const unsigned short* __restrict__ qh,
                                               const unsigned short* __restrict__ ql,
                                               unsigned short* __restrict__ oh,
                                               unsigned short* __restrict__ ol,
                                               const int* __restrict__ cntp)
{
    constexpr int NP = SPLIT ? 2 : 1;
    constexpr int PVK = PVKT * 32;
    constexpr int QT = (S + 15) / 16;
    extern __shared__ unsigned short sh[];
    unsigned short* VT = sh;
    unsigned short* PL = sh + NP * 64 * PSTR;

    const int h = blockIdx.x, b = blockIdx.y;
    const int tid = threadIdx.x, w = tid >> 6, lane = tid & 63;
    const int nk = cntp ? cntp[b] : S;
    const size_t qbase = (size_t)b * S * 2304 + (size_t)h * 64;
    const int fr = lane & 15, fq = lane >> 4;

    for (int j0 = 0; j0 < S; j0 += 32) {
        int j = j0 + (tid >> 3);
        int d8 = (tid & 7) * 8;
        if (j < S) {
            size_t src = qbase + (size_t)j * 2304 + 1536 + d8;
#pragma unroll
            for (int p = 0; p < NP; p++) {
                const unsigned short* qp = p ? ql : qh;
                short8 v = *(const short8*)(qp + src);
#pragma unroll
                for (int e = 0; e < 8; e++)
                    VT[p * 64 * PSTR + (d8 + e) * PSTR + j] = ((unsigned short*)&v)[e];
            }
        }
    }
    for (int idx = tid; idx < 64 * (PVK - S); idx += 256) {
        int d = idx / (PVK - S), j = S + idx % (PVK - S);
#pragma unroll
        for (int p = 0; p < NP; p++) VT[p * 64 * PSTR + d * PSTR + j] = 0;
    }
    {
        unsigned short* Pw = PL + w * NP * 16 * PSTR;
        for (int idx = lane; idx < 16 * (PVK - 16 * KT); idx += 64) {
            int rr = idx / (PVK - 16 * KT), cc = 16 * KT + idx % (PVK - 16 * KT);
#pragma unroll
            for (int p = 0; p < NP; p++) Pw[p * 16 * PSTR + rr * PSTR + cc] = 0;
        }
    }
    __syncthreads();

    for (int qt = w; qt < QT; qt += 4) {
        int qr = qt * 16 + fr; int qrc = qr < S ? qr : S - 1;
        const size_t qrow = qbase + (size_t)qrc * 2304;
        short8 qf0[2], qf1[2];
#pragma unroll
        for (int ks = 0; ks < 2; ks++) {
            qf0[ks] = *(const short8*)(qh + qrow + ks * 32 + fq * 8);
            if (SPLIT) qf1[ks] = *(const short8*)(ql + qrow + ks * 32 + fq * 8);
        }
        f32x4 sc[KT];
#pragma unroll
        for (int kt = 0; kt < KT; kt++) {
            int ky = kt * 16 + fr; int kyc = ky < S ? ky : S - 1;
            const size_t krow = qbase + (size_t)kyc * 2304 + 768;
            f32x4 acc = (f32x4)0.f;
#pragma unroll
            for (int ks = 0; ks < 2; ks++) {
                short8 kh = *(const short8*)(qh + krow + ks * 32 + fq * 8);
                acc = __builtin_amdgcn_mfma_f32_16x16x32_bf16(qf0[ks], kh, acc, 0, 0, 0);
                if (SPLIT) {
                    short8 kl = *(const short8*)(ql + krow + ks * 32 + fq * 8);
                    acc = __builtin_amdgcn_mfma_f32_16x16x32_bf16(qf0[ks], kl, acc, 0, 0, 0);
                    acc = __builtin_amdgcn_mfma_f32_16x16x32_bf16(qf1[ks], kh, acc, 0, 0, 0);
                }
            }
            sc[kt] = acc;
        }
        float mx[4] = {-3e38f, -3e38f, -3e38f, -3e38f};
#pragma unroll
        for (int kt = 0; kt < KT; kt++) {
            bool valid = (kt * 16 + fr) < nk;
#pragma unroll
            for (int r = 0; r < 4; r++) {
                float s = sc[kt][r] * 0.125f;
                sc[kt][r] = s;
                if (valid) mx[r] = fmaxf(mx[r], s);
            }
        }
#pragma unroll
        for (int off = 1; off < 16; off <<= 1)
#pragma unroll
            for (int r = 0; r < 4; r++) mx[r] = fmaxf(mx[r], __shfl_xor(mx[r], off));
        float sum[4] = {0.f, 0.f, 0.f, 0.f};
#pragma unroll
        for (int kt = 0; kt < KT; kt++) {
            bool valid = (kt * 16 + fr) < nk;
#pragma unroll
            for (int r = 0; r < 4; r++) {
                float p = 0.f;
                if (valid) p = SPLIT ? expf(sc[kt][r] - mx[r]) : __expf(sc[kt][r] - mx[r]);
                sc[kt][r] = p;
                sum[r] += p;
            }
        }
#pragma unroll
        for (int off = 1; off < 16; off <<= 1)
#pragma unroll
            for (int r = 0; r < 4; r++) sum[r] += __shfl_xor(sum[r], off);
        float inv[4];
#pragma unroll
        for (int r = 0; r < 4; r++) inv[r] = 1.f / sum[r];
        unsigned short* Pw = PL + w * NP * 16 * PSTR;
#pragma unroll
        for (int kt = 0; kt < KT; kt++) {
#pragma unroll
            for (int r = 0; r < 4; r++) {
                float p = sc[kt][r] * inv[r];
                unsigned short hh = f2bf(p);
                Pw[(fq * 4 + r) * PSTR + kt * 16 + fr] = hh;
                if (SPLIT) Pw[16 * PSTR + (fq * 4 + r) * PSTR + kt * 16 + fr] = f2bf(p - bf2f(hh));
            }
        }
        f32x4 o[4];
#pragma unroll
        for (int n = 0; n < 4; n++) o[n] = (f32x4)0.f;
#pragma unroll
        for (int ks = 0; ks < PVKT; ks++) {
            short8 pa = *(const short8*)(Pw + fr * PSTR + ks * 32 + fq * 8);
            short8 pl2;
            if (SPLIT) pl2 = *(const short8*)(Pw + 16 * PSTR + fr * PSTR + ks * 32 + fq * 8);
#pragma unroll
            for (int n = 0; n < 4; n++) {
                short8 vb = *(const short8*)(VT + (n * 16 + fr) * PSTR + ks * 32 + fq * 8);
                o[n] = __builtin_amdgcn_mfma_f32_16x16x32_bf16(pa, vb, o[n], 0, 0, 0);
                if (SPLIT) {
                    short8 vl = *(const short8*)(VT + 64 * PSTR + (n * 16 + fr) * PSTR + ks * 32 + fq * 8);
                    o[n] = __builtin_amdgcn_mfma_f32_16x16x32_bf16(pa, vl, o[n], 0, 0, 0);
                    o[n] = __builtin_amdgcn_mfma_f32_16x16x32_bf16(pl2, vb, o[n], 0, 0, 0);
                }
            }
        }
#pragma unroll
        for (int n = 0; n < 4; n++) {
#pragma unroll
            for (int r = 0; r < 4; r++) {
                int row = qt * 16 + fq * 4 + r;
                if (row < S) {
                    size_t oidx = ((size_t)b * S + row) * 768 + (size_t)h * 64 + n * 16 + fr;
                    float vv = o[n][r];
                    unsigned short hh = f2bf(vv);
                    oh[oidx] = hh;
                    if (SPLIT) ol[oidx] = f2bf(vv - bf2f(hh));
                }
            }
        }
    }
}

// ---------------------------------------------------------------- prune machinery
__global__ __launch_bounds__(256) void normsq_k(const float* __restrict__ x, float* __restrict__ norms)
{
    const float* xr = x + (size_t)blockIdx.x * 768;
    int t = threadIdx.x;
    float v0 = xr[t], v1 = xr[t + 256], v2 = xr[t + 512];
    float ss = v0 * v0 + v1 * v1 + v2 * v2;
#pragma unroll
    for (int o = 32; o; o >>= 1) ss += __shfl_xor(ss, o);
    __shared__ float r1[4];
    if ((t & 63) == 0) r1[t >> 6] = ss;
    __syncthreads();
    if (t == 0) norms[blockIdx.x] = r1[0] + r1[1] + r1[2] + r1[3];
}

__global__ __launch_bounds__(256) void topk_k(const float* __restrict__ norms,
                                              int* __restrict__ idxmap, int* __restrict__ cnt)
{
    int b = blockIdx.x, t = threadIdx.x;
    __shared__ float n[NTOK];
    __shared__ unsigned char kp[NTOK];
    if (t < NTOK) n[t] = norms[b * NTOK + t];
    __syncthreads();
    if (t < NTOK) {
        float me = n[t];
        int rank = 0;
        for (int j = 0; j < NTOK; j++) rank += (n[j] > me) || (n[j] == me && j < t);
        kp[t] = (rank < 98) || (t == 0);
    }
    __syncthreads();
    if (t == 0) {
        int c = 0;
        for (int s = 0; s < NTOK; s++) if (kp[s]) idxmap[b * SL + c++] = s;
        cnt[b] = c;
        for (int j = c; j < SL; j++) idxmap[b * SL + j] = 0;
    }
}

__global__ __launch_bounds__(256) void gather_k(const float* __restrict__ x, const int* __restrict__ idxmap,
                                                const int* __restrict__ cnt, float* __restrict__ xl)
{
    int j = blockIdx.x, b = blockIdx.y;
    size_t dst = ((size_t)b * SL + j) * 768;
    if (j < cnt[b]) {
        int s = idxmap[b * SL + j];
        size_t src = ((size_t)b * NTOK + s) * 768;
        for (int d = threadIdx.x; d < 768; d += 256) xl[dst + d] = x[src + d];
    } else {
        for (int d = threadIdx.x; d < 768; d += 256) xl[dst + d] = 0.f;
    }
}

// ---------------------------------------------------------------- launch
extern "C" void kernel_launch(void* const* d_in, const int* in_sizes, int n_in,
                              void* d_out, int out_size, void* d_ws, size_t ws_size,
                              hipStream_t stream)
{
    const float* images  = (const float*)d_in[0];
    const float* patch_w = (const float*)d_in[1];
    const float* patch_b = (const float*)d_in[2];
    const float* cls_tok = (const float*)d_in[3];
    const float* pos_emb = (const float*)d_in[4];
    const float* ln1_g   = (const float*)d_in[5];
    const float* ln1_b   = (const float*)d_in[6];
    const float* qkv_w   = (const float*)d_in[7];
    const float* qkv_b   = (const float*)d_in[8];
    const float* proj_w  = (const float*)d_in[9];
    const float* proj_b  = (const float*)d_in[10];
    const float* ln2_g   = (const float*)d_in[11];
    const float* ln2_b   = (const float*)d_in[12];
    const float* fc1_w   = (const float*)d_in[13];
    const float* fc1_b   = (const float*)d_in[14];
    const float* fc2_w   = (const float*)d_in[15];
    const float* fc2_b   = (const float*)d_in[16];
    const float* norm_g  = (const float*)d_in[17];
    const float* norm_b  = (const float*)d_in[18];
    const float* head_w  = (const float*)d_in[19];
    const float* head_b  = (const float*)d_in[20];
    float* outp = (float*)d_out;

    char* W = (char*)d_ws;
    float* x = (float*)W;                                       // 38,731,776
    unsigned short* hbh = (unsigned short*)(W + 38731776);
    unsigned short* hbl = hbh + 9682944;
    char* R = W + 77463552;
    unsigned short* wbh = (unsigned short*)(W + 232390656);
    unsigned short* wbl = wbh + 7077888;
    unsigned short* pwh = (unsigned short*)(W + 260702208);
    unsigned short* pwl = pwh + 589824;
    unsigned short* hwb = (unsigned short*)(W + 263061504);
    float* norms = (float*)(W + 264634368);
    unsigned short* clsb = (unsigned short*)(W + 264684800);
    int* idxmap = (int*)(W + 264881408);
    int* cnt    = (int*)(W + 264906752);

    unsigned short* ph  = (unsigned short*)R;
    unsigned short* plo = ph + 9633792;
    float* emb = (float*)(R + 38535168);
    unsigned short* qkh = (unsigned short*)R;
    unsigned short* qkl = qkh + 29048832;
    unsigned short* ffh = (unsigned short*)R;
    unsigned short* ffl = ffh + 38731776;
    float* xl = (float*)(R + 41943040);

    const int LDS_EARLY = (2 * 64 * 232 + 4 * 2 * 16 * 232) * 2;   // 118,784
    const int LDS_LATE  = (1 * 64 * 136 + 4 * 1 * 16 * 136) * 2;   // 34,816
    (void)hipFuncSetAttribute(reinterpret_cast<const void*>(&attn2_k<1, 197, 13, 7, 232>),
                              hipFuncAttributeMaxDynamicSharedMemorySize, LDS_EARLY);
    (void)hipFuncSetAttribute(reinterpret_cast<const void*>(&attn2_k<0, 99, 7, 4, 136>),
                              hipFuncAttributeMaxDynamicSharedMemorySize, LDS_LATE);

    // grid helpers: nR tiles of 128 rows, nC tiles of 128 cols
    // MAP1/2 grids: 8 * nRmax * nC
    const int nR1 = 99, nRm1 = 13;     // M = 12608
    const int nRp = 98, nRmp = 13;     // patch M = 12544
    const int nR2 = 50, nRm2 = 7;      // M = 6336

    // ---- patch embed (split) ----
    cvt_simple_k<1><<<576, 256, 0, stream>>>(patch_w, pwh, pwl, 147456);
    patch_extract2_k<<<dim3(196, NB), 256, 0, stream>>>(images, ph, plo);
    mgemm_k<1, 0, 0, 2><<<8 * nRmp * 6, 256, 0, stream>>>(ph, plo, pwh, pwl, patch_b, nullptr,
        nullptr, nullptr, emb, 12544, 768, 768, nRp, 6, nRmp);
    assemble_k<<<dim3(NTOK, NB), 256, 0, stream>>>(emb, cls_tok, pos_emb, x);

    const int M1 = NB * NTOK;   // 12608
    for (int i = 0; i < 4; i++) {
        cvt_layer_k<1><<<6912, 256, 0, stream>>>(qkv_w + (size_t)i * 1769472, proj_w + (size_t)i * 589824,
                                                 fc1_w + (size_t)i * 2359296, fc2_w + (size_t)i * 2359296,
                                                 wbh, wbl);
        ln2_k<2><<<M1, 256, 0, stream>>>(x, hbh, hbl, ln1_g + (size_t)i * 768, ln1_b + (size_t)i * 768, 768);
        mgemm_k<1, 0, 2, 1><<<8 * nRm1 * 18, 256, 0, stream>>>(hbh, hbl, wbh, wbl,
            qkv_b + (size_t)i * 2304, nullptr, qkh, qkl, nullptr, M1, 2304, 768, nR1, 18, nRm1);
        attn2_k<1, 197, 13, 7, 232><<<dim3(NHEAD, NB), 256, LDS_EARLY, stream>>>(qkh, qkl, hbh, hbl, nullptr);
        mgemm_k<1, 2, 0, 2><<<8 * nRm1 * 6, 256, 0, stream>>>(hbh, hbl, wbh + 1769472, wbl + 1769472,
            proj_b + (size_t)i * 768, x, nullptr, nullptr, x, M1, 768, 768, nR1, 6, nRm1);
        ln2_k<2><<<M1, 256, 0, stream>>>(x, hbh, hbl, ln2_g + (size_t)i * 768, ln2_b + (size_t)i * 768, 768);
        mgemm_k<1, 1, 2, 1><<<8 * nRm1 * 24, 256, 0, stream>>>(hbh, hbl, wbh + 2359296, wbl + 2359296,
            fc1_b + (size_t)i * 3072, nullptr, ffh, ffl, nullptr, M1, 3072, 768, nR1, 24, nRm1);
        mgemm_k<1, 2, 0, 2><<<8 * nRm1 * 6, 256, 0, stream>>>(ffh, ffl, wbh + 4718592, wbl + 4718592,
            fc2_b + (size_t)i * 768, x, nullptr, nullptr, x, M1, 768, 3072, nR1, 6, nRm1);
    }

    // ---- prune + compact ----
    normsq_k<<<M1, 256, 0, stream>>>(x, norms);
    topk_k<<<NB, 256, 0, stream>>>(norms, idxmap, cnt);
    gather_k<<<dim3(SL, NB), 256, 0, stream>>>(x, idxmap, cnt, xl);

    const int M2 = NB * SL;     // 6336
    for (int i = 4; i < 12; i++) {
        cvt_layer_k<0><<<6912, 256, 0, stream>>>(qkv_w + (size_t)i * 1769472, proj_w + (size_t)i * 589824,
                                                 fc1_w + (size_t)i * 2359296, fc2_w + (size_t)i * 2359296,
                                                 wbh, nullptr);
        ln2_k<1><<<M2, 256, 0, stream>>>(xl, hbh, nullptr, ln1_g + (size_t)i * 768, ln1_b + (size_t)i * 768, 768);
        mgemm_k<0, 0, 1, 1><<<8 * nRm2 * 18, 256, 0, stream>>>(hbh, nullptr, wbh, nullptr,
            qkv_b + (size_t)i * 2304, nullptr, qkh, nullptr, nullptr, M2, 2304, 768, nR2, 18, nRm2);
        attn2_k<0, 99, 7, 4, 136><<<dim3(NHEAD, NB), 256, LDS_LATE, stream>>>(qkh, nullptr, hbl, nullptr, cnt);
        mgemm_k<0, 2, 0, 2><<<8 * nRm2 * 6, 256, 0, stream>>>(hbl, nullptr, wbh + 1769472, nullptr,
            proj_b + (size_t)i * 768, xl, nullptr, nullptr, xl, M2, 768, 768, nR2, 6, nRm2);
        ln2_k<1><<<M2, 256, 0, stream>>>(xl, hbh, nullptr, ln2_g + (size_t)i * 768, ln2_b + (size_t)i * 768, 768);
        mgemm_k<0, 1, 1, 1><<<8 * nRm2 * 24, 256, 0, stream>>>(hbh, nullptr, wbh + 2359296, nullptr,
            fc1_b + (size_t)i * 3072, nullptr, ffh, nullptr, nullptr, M2, 3072, 768, nR2, 24, nRm2);
        mgemm_k<0, 2, 0, 2><<<8 * nRm2 * 6, 256, 0, stream>>>(ffh, nullptr, wbh + 4718592, nullptr,
            fc2_b + (size_t)i * 768, xl, nullptr, nullptr, xl, M2, 768, 3072, nR2, 6, nRm2);
    }

    // ---- final LN(CLS) + head ----
    ln2_k<1><<<NB, 256, 0, stream>>>(xl, clsb, nullptr, norm_g, norm_b, (size_t)SL * 768);
    cvt_simple_k<0><<<750, 256, 0, stream>>>(head_w, hwb, nullptr, 192000);
    mgemm_k<0, 0, 0, 0><<<8, 256, 0, stream>>>(clsb, nullptr, hwb, nullptr,
        head_b, nullptr, nullptr, nullptr, outp, 64, 1000, 768, 1, 8, 1);
}

// Round 4
// 5693.826 us; speedup vs baseline: 5.4457x; 1.0459x over previous
//
#include <hip/hip_runtime.h>
#include <cstdint>
#include <cstddef>

// ViT-B/16 + token pruning. Round 4: counted-vmcnt K-loop (T4) in mgemm_k —
// raw s_barrier, prefetch depth 2, never drain vmcnt to 0 in the main loop.
// Split bf16 (3-MFMA) pre-prune, plain bf16 post-prune.

#define NTOK 197
#define NB 64
#define NHEAD 12
#define SL 99

typedef __attribute__((ext_vector_type(8))) short short8;
typedef __attribute__((ext_vector_type(4))) float f32x4;
typedef __attribute__((ext_vector_type(4))) unsigned short us4;

#define DEV static __device__ __forceinline__

DEV unsigned short f2bf(float f) {
    union { float f; unsigned int u; } v; v.f = f;
    unsigned int r = (v.u + 0x7FFFu + ((v.u >> 16) & 1u)) >> 16;
    return (unsigned short)r;
}
DEV float bf2f(unsigned short h) {
    union { float f; unsigned int u; } v; v.u = ((unsigned int)h) << 16;
    return v.f;
}
DEV void gload16(const void* g, void* l) {
    __builtin_amdgcn_global_load_lds((const __attribute__((address_space(1))) unsigned int*)g,
                                     (__attribute__((address_space(3))) unsigned int*)l, 16, 0, 0);
}

// ---------------------------------------------------------------- weight conversion
template<int SP>
__global__ __launch_bounds__(256) void cvt_layer_k(const float* __restrict__ qw,
                                                   const float* __restrict__ pw,
                                                   const float* __restrict__ f1,
                                                   const float* __restrict__ f2,
                                                   unsigned short* __restrict__ dh,
                                                   unsigned short* __restrict__ dl)
{
    size_t t = (size_t)blockIdx.x * 256 + threadIdx.x;
    size_t e = t * 4;
    const float* src; size_t loc;
    if (e < 1769472)      { src = qw; loc = e; }
    else if (e < 2359296) { src = pw; loc = e - 1769472; }
    else if (e < 4718592) { src = f1; loc = e - 2359296; }
    else                  { src = f2; loc = e - 4718592; }
    float4 v = *(const float4*)(src + loc);
    us4 hi; hi.x = f2bf(v.x); hi.y = f2bf(v.y); hi.z = f2bf(v.z); hi.w = f2bf(v.w);
    *(us4*)(dh + e) = hi;
    if (SP) {
        us4 lo;
        lo.x = f2bf(v.x - bf2f(hi.x)); lo.y = f2bf(v.y - bf2f(hi.y));
        lo.z = f2bf(v.z - bf2f(hi.z)); lo.w = f2bf(v.w - bf2f(hi.w));
        *(us4*)(dl + e) = lo;
    }
}

template<int SP>
__global__ __launch_bounds__(256) void cvt_simple_k(const float* __restrict__ src,
                                                    unsigned short* __restrict__ dh,
                                                    unsigned short* __restrict__ dl, int n4)
{
    int t = blockIdx.x * 256 + threadIdx.x;
    if (t >= n4) return;
    size_t e = (size_t)t * 4;
    float4 v = *(const float4*)(src + e);
    us4 hi; hi.x = f2bf(v.x); hi.y = f2bf(v.y); hi.z = f2bf(v.z); hi.w = f2bf(v.w);
    *(us4*)(dh + e) = hi;
    if (SP) {
        us4 lo;
        lo.x = f2bf(v.x - bf2f(hi.x)); lo.y = f2bf(v.y - bf2f(hi.y));
        lo.z = f2bf(v.z - bf2f(hi.z)); lo.w = f2bf(v.w - bf2f(hi.w));
        *(us4*)(dl + e) = lo;
    }
}

// ---------------------------------------------------------------- patch extract
__global__ __launch_bounds__(256) void patch_extract2_k(const float* __restrict__ img,
                                                        unsigned short* __restrict__ ph,
                                                        unsigned short* __restrict__ pl)
{
    int pi = blockIdx.x, b = blockIdx.y;
    int gy = pi / 14, gx = pi % 14;
    size_t obase = ((size_t)b * 196 + pi) * 768;
    for (int f = threadIdx.x; f < 768; f += 256) {
        int c = f >> 8, py = (f >> 4) & 15, px = f & 15;
        float v = img[(((size_t)b * 3 + c) * 224 + gy * 16 + py) * 224 + gx * 16 + px];
        unsigned short hi = f2bf(v);
        ph[obase + f] = hi;
        pl[obase + f] = f2bf(v - bf2f(hi));
    }
}

__global__ __launch_bounds__(256) void assemble_k(const float* __restrict__ emb,
                                                  const float* __restrict__ cls,
                                                  const float* __restrict__ pos,
                                                  float* __restrict__ x)
{
    int s = blockIdx.x, b = blockIdx.y;
    size_t xo = ((size_t)b * NTOK + s) * 768;
    for (int d = threadIdx.x; d < 768; d += 256) {
        float v = (s == 0) ? cls[d] : emb[((size_t)b * 196 + (s - 1)) * 768 + d];
        x[xo + d] = v + pos[(size_t)s * 768 + d];
    }
}

// ---------------------------------------------------------------- layernorm fp32 -> bf16 (OS=2: +lo plane)
template<int OS>
__global__ __launch_bounds__(256) void ln2_k(const float* __restrict__ in,
                                             unsigned short* __restrict__ outh,
                                             unsigned short* __restrict__ outl,
                                             const float* __restrict__ g,
                                             const float* __restrict__ bt, size_t ldin)
{
    const float* xr = in + (size_t)blockIdx.x * ldin;
    size_t ob = (size_t)blockIdx.x * 768;
    int t = threadIdx.x;
    float v0 = xr[t], v1 = xr[t + 256], v2 = xr[t + 512];
    float s = v0 + v1 + v2;
#pragma unroll
    for (int o = 32; o; o >>= 1) s += __shfl_xor(s, o);
    __shared__ float r1[4], r2[4];
    int wv = t >> 6, ln = t & 63;
    if (ln == 0) r1[wv] = s;
    __syncthreads();
    float mean = (r1[0] + r1[1] + r1[2] + r1[3]) * (1.f / 768.f);
    float d0 = v0 - mean, d1 = v1 - mean, d2 = v2 - mean;
    float ss = d0 * d0 + d1 * d1 + d2 * d2;
#pragma unroll
    for (int o = 32; o; o >>= 1) ss += __shfl_xor(ss, o);
    if (ln == 0) r2[wv] = ss;
    __syncthreads();
    float inv = rsqrtf((r2[0] + r2[1] + r2[2] + r2[3]) * (1.f / 768.f) + 1e-6f);
    float y0 = d0 * inv * g[t] + bt[t];
    float y1 = d1 * inv * g[t + 256] + bt[t + 256];
    float y2 = d2 * inv * g[t + 512] + bt[t + 512];
    unsigned short h0 = f2bf(y0), h1 = f2bf(y1), h2 = f2bf(y2);
    outh[ob + t] = h0; outh[ob + t + 256] = h1; outh[ob + t + 512] = h2;
    if (OS == 2) {
        outl[ob + t] = f2bf(y0 - bf2f(h0));
        outl[ob + t + 256] = f2bf(y1 - bf2f(h1));
        outl[ob + t + 512] = f2bf(y2 - bf2f(h2));
    }
}

// ---------------------------------------------------------------- MFMA GEMM, counted-vmcnt pipeline
// A[M,K], W[N,K] bf16 (split: hi/lo planes). 128x128 tile, BK=32, 4 waves.
// MAP: 0 linear, 1 xcd rows-fastest, 2 xcd cols-fastest.
// Pipeline: prefetch depth 2, raw s_barrier, vmcnt(LOADS) in steady state
// (never 0 until the last iteration). lgkmcnt(0)+sched_barrier before the
// second barrier so stage(t+2) can't overwrite a buffer still being read.
template<int SPLIT, int EPI, int OS, int MAP>
__global__ __launch_bounds__(256) void mgemm_k(const unsigned short* __restrict__ Ah,
                                               const unsigned short* __restrict__ Al,
                                               const unsigned short* __restrict__ Wh,
                                               const unsigned short* __restrict__ Wl,
                                               const float* __restrict__ bias,
                                               const float* __restrict__ res,
                                               unsigned short* __restrict__ Chi,
                                               unsigned short* __restrict__ Clo,
                                               float* __restrict__ Cf,
                                               int M, int N, int K, int nR, int nC, int nRmax)
{
    constexpr int NP = SPLIT ? 2 : 1;
    __shared__ unsigned short lds[2 * NP * 8192];   // [buf][A|B][plane][128 rows][32]

    int rt, ct;
    {
        int bid = blockIdx.x;
        if (MAP == 0) { rt = bid % nR; ct = bid / nR; }
        else {
            int x = bid & 7, u = bid >> 3, rl, c;
            if (MAP == 2) { c = u % nC; rl = u / nC; }
            else          { rl = u % nRmax; c = u / nRmax; }
            rt = x + 8 * rl; ct = c;
            if (rt >= nR) return;
        }
    }
    const int row0 = rt << 7, col0 = ct << 7;
    const int tid = threadIdx.x;
    const int w = tid >> 6, lane = tid & 63;
    const int wr = w >> 1, wc = w & 1;
    const int srow = lane >> 2;
    const int schunk = ((lane & 3) ^ ((srow >> 1) & 3)) << 3;  // pre-swizzled source chunk
    const int fr = lane & 15, fq = lane >> 4;
    const int rchunk = (fq ^ ((fr >> 1) & 3)) << 3;            // swizzled read chunk

    f32x4 acc[4][4];
#pragma unroll
    for (int m = 0; m < 4; m++)
#pragma unroll
        for (int n = 0; n < 4; n++) acc[m][n] = (f32x4)0.f;

    const int nk = K >> 5;   // always >= 2 here (K = 768 or 3072)

    auto stage = [&](int t, int bsel) {
        const int k0 = t << 5;
        unsigned short* Ad = lds + bsel * NP * 8192;
        unsigned short* Bd = Ad + NP * 4096;
#pragma unroll
        for (int p = 0; p < NP; p++) {
            const unsigned short* Ap = p ? Al : Ah;
            const unsigned short* Wp = p ? Wl : Wh;
#pragma unroll
            for (int i = 0; i < 2; i++) {
                int r = i * 64 + w * 16 + srow;
                int ga = row0 + r; if (ga > M - 1) ga = M - 1;
                int gb = col0 + r; if (gb > N - 1) gb = N - 1;
                gload16(Ap + (size_t)ga * K + k0 + schunk, Ad + p * 4096 + i * 2048 + w * 512);
                gload16(Wp + (size_t)gb * K + k0 + schunk, Bd + p * 4096 + i * 2048 + w * 512);
            }
        }
    };

    stage(0, 0);
    stage(1, 1);
    for (int t = 0; t < nk; ++t) {
        const int bsel = t & 1;
        // wait for tile t's loads; keep tile t+1's (NP*4 per wave) in flight
        if (t + 1 < nk) {
            if constexpr (NP == 2) asm volatile("s_waitcnt vmcnt(8)" ::: "memory");
            else                   asm volatile("s_waitcnt vmcnt(4)" ::: "memory");
        } else {
            asm volatile("s_waitcnt vmcnt(0)" ::: "memory");
        }
        __builtin_amdgcn_s_barrier();              // all waves' tile-t loads landed
        __builtin_amdgcn_sched_barrier(0);
        const unsigned short* Ab = lds + bsel * NP * 8192;
        const unsigned short* Bb = Ab + NP * 4096;
        short8 a[NP][4], bb[NP][4];
#pragma unroll
        for (int p = 0; p < NP; p++)
#pragma unroll
            for (int m = 0; m < 4; m++)
                a[p][m] = *(const short8*)(Ab + p * 4096 + (wr * 64 + m * 16 + fr) * 32 + rchunk);
#pragma unroll
        for (int p = 0; p < NP; p++)
#pragma unroll
            for (int n = 0; n < 4; n++)
                bb[p][n] = *(const short8*)(Bb + p * 4096 + (wc * 64 + n * 16 + fr) * 32 + rchunk);
        __builtin_amdgcn_sched_barrier(0);
        asm volatile("s_waitcnt lgkmcnt(0)" ::: "memory");   // my reads retired
        __builtin_amdgcn_sched_barrier(0);
        __builtin_amdgcn_s_barrier();              // everyone done reading buf bsel
        if (t + 2 < nk) stage(t + 2, bsel);        // safe to overwrite; issue before MFMA
#pragma unroll
        for (int m = 0; m < 4; m++)
#pragma unroll
            for (int n = 0; n < 4; n++) {
                acc[m][n] = __builtin_amdgcn_mfma_f32_16x16x32_bf16(a[0][m], bb[0][n], acc[m][n], 0, 0, 0);
                if (SPLIT) {
                    acc[m][n] = __builtin_amdgcn_mfma_f32_16x16x32_bf16(a[0][m], bb[1][n], acc[m][n], 0, 0, 0);
                    acc[m][n] = __builtin_amdgcn_mfma_f32_16x16x32_bf16(a[1][m], bb[0][n], acc[m][n], 0, 0, 0);
                }
            }
    }

#pragma unroll
    for (int m = 0; m < 4; m++) {
#pragma unroll
        for (int n = 0; n < 4; n++) {
            int col = col0 + wc * 64 + n * 16 + fr;
#pragma unroll
            for (int r = 0; r < 4; r++) {
                int row = row0 + wr * 64 + m * 16 + fq * 4 + r;
                if (row < M && col < N) {
                    float v = acc[m][n][r] + bias[col];
                    size_t o = (size_t)row * N + col;
                    if (EPI == 2) v += res[o];
                    if (EPI == 1) v = 0.5f * v * (1.f + erff(v * 0.70710678118654752f));
                    if (OS == 0) Cf[o] = v;
                    else if (OS == 1) Chi[o] = f2bf(v);
                    else { unsigned short hh = f2bf(v); Chi[o] = hh; Clo[o] = f2bf(v - bf2f(hh)); }
                }
            }
        }
    }
}

// ---------------------------------------------------------------- fused MFMA attention
template<int SPLIT, int S, int KT, int PVKT, int PSTR>
__global__ __launch_bounds__(256) void attn2_k(const unsigned short* __restrict__ qh,
                                               const unsigned short* __restrict__ ql,
                                               unsigned short* __restrict__ oh,
                                               unsigned short* __restrict__ ol,
                                               const int* __restrict__ cntp)
{
    constexpr int NP = SPLIT ? 2 : 1;
    constexpr int PVK = PVKT * 32;
    constexpr int QT = (S + 15) / 16;
    extern __shared__ unsigned short sh[];
    unsigned short* VT = sh;
    unsigned short* PL = sh + NP * 64 * PSTR;

    const int h = blockIdx.x, b = blockIdx.y;
    const int tid = threadIdx.x, w = tid >> 6, lane = tid & 63;
    const int nk = cntp ? cntp[b] : S;
    const size_t qbase = (size_t)b * S * 2304 + (size_t)h * 64;
    const int fr = lane & 15, fq = lane >> 4;

    for (int j0 = 0; j0 < S; j0 += 32) {
        int j = j0 + (tid >> 3);
        int d8 = (tid & 7) * 8;
        if (j < S) {
            size_t src = qbase + (size_t)j * 2304 + 1536 + d8;
#pragma unroll
            for (int p = 0; p < NP; p++) {
                const unsigned short* qp = p ? ql : qh;
                short8 v = *(const short8*)(qp + src);
#pragma unroll
                for (int e = 0; e < 8; e++)
                    VT[p * 64 * PSTR + (d8 + e) * PSTR + j] = ((unsigned short*)&v)[e];
            }
        }
    }
    for (int idx = tid; idx < 64 * (PVK - S); idx += 256) {
        int d = idx / (PVK - S), j = S + idx % (PVK - S);
#pragma unroll
        for (int p = 0; p < NP; p++) VT[p * 64 * PSTR + d * PSTR + j] = 0;
    }
    {
        unsigned short* Pw = PL + w * NP * 16 * PSTR;
        for (int idx = lane; idx < 16 * (PVK - 16 * KT); idx += 64) {
            int rr = idx / (PVK - 16 * KT), cc = 16 * KT + idx % (PVK - 16 * KT);
#pragma unroll
            for (int p = 0; p < NP; p++) Pw[p * 16 * PSTR + rr * PSTR + cc] = 0;
        }
    }
    __syncthreads();

    for (int qt = w; qt < QT; qt += 4) {
        int qr = qt * 16 + fr; int qrc = qr < S ? qr : S - 1;
        const size_t qrow = qbase + (size_t)qrc * 2304;
        short8 qf0[2], qf1[2];
#pragma unroll
        for (int ks = 0; ks < 2; ks++) {
            qf0[ks] = *(const short8*)(qh + qrow + ks * 32 + fq * 8);
            if (SPLIT) qf1[ks] = *(const short8*)(ql + qrow + ks * 32 + fq * 8);
        }
        f32x4 sc[KT];
#pragma unroll
        for (int kt = 0; kt < KT; kt++) {
            int ky = kt * 16 + fr; int kyc = ky < S ? ky : S - 1;
            const size_t krow = qbase + (size_t)kyc * 2304 + 768;
            f32x4 acc = (f32x4)0.f;
#pragma unroll
            for (int ks = 0; ks < 2; ks++) {
                short8 kh = *(const short8*)(qh + krow + ks * 32 + fq * 8);
                acc = __builtin_amdgcn_mfma_f32_16x16x32_bf16(qf0[ks], kh, acc, 0, 0, 0);
                if (SPLIT) {
                    short8 kl = *(const short8*)(ql + krow + ks * 32 + fq * 8);
                    acc = __builtin_amdgcn_mfma_f32_16x16x32_bf16(qf0[ks], kl, acc, 0, 0, 0);
                    acc = __builtin_amdgcn_mfma_f32_16x16x32_bf16(qf1[ks], kh, acc, 0, 0, 0);
                }
            }
            sc[kt] = acc;
        }
        float mx[4] = {-3e38f, -3e38f, -3e38f, -3e38f};
#pragma unroll
        for (int kt = 0; kt < KT; kt++) {
            bool valid = (kt * 16 + fr) < nk;
#pragma unroll
            for (int r = 0; r < 4; r++) {
                float s = sc[kt][r] * 0.125f;
                sc[kt][r] = s;
                if (valid) mx[r] = fmaxf(mx[r], s);
            }
        }
#pragma unroll
        for (int off = 1; off < 16; off <<= 1)
#pragma unroll
            for (int r = 0; r < 4; r++) mx[r] = fmaxf(mx[r], __shfl_xor(mx[r], off));
        float sum[4] = {0.f, 0.f, 0.f, 0.f};
#pragma unroll
        for (int kt = 0; kt < KT; kt++) {
            bool valid = (kt * 16 + fr) < nk;
#pragma unroll
            for (int r = 0; r < 4; r++) {
                float p = 0.f;
                if (valid) p = SPLIT ? expf(sc[kt][r] - mx[r]) : __expf(sc[kt][r] - mx[r]);
                sc[kt][r] = p;
                sum[r] += p;
            }
        }
#pragma unroll
        for (int off = 1; off < 16; off <<= 1)
#pragma unroll
            for (int r = 0; r < 4; r++) sum[r] += __shfl_xor(sum[r], off);
        float inv[4];
#pragma unroll
        for (int r = 0; r < 4; r++) inv[r] = 1.f / sum[r];
        unsigned short* Pw = PL + w * NP * 16 * PSTR;
#pragma unroll
        for (int kt = 0; kt < KT; kt++) {
#pragma unroll
            for (int r = 0; r < 4; r++) {
                float p = sc[kt][r] * inv[r];
                unsigned short hh = f2bf(p);
                Pw[(fq * 4 + r) * PSTR + kt * 16 + fr] = hh;
                if (SPLIT) Pw[16 * PSTR + (fq * 4 + r) * PSTR + kt * 16 + fr] = f2bf(p - bf2f(hh));
            }
        }
        f32x4 o[4];
#pragma unroll
        for (int n = 0; n < 4; n++) o[n] = (f32x4)0.f;
#pragma unroll
        for (int ks = 0; ks < PVKT; ks++) {
            short8 pa = *(const short8*)(Pw + fr * PSTR + ks * 32 + fq * 8);
            short8 pl2;
            if (SPLIT) pl2 = *(const short8*)(Pw + 16 * PSTR + fr * PSTR + ks * 32 + fq * 8);
#pragma unroll
            for (int n = 0; n < 4; n++) {
                short8 vb = *(const short8*)(VT + (n * 16 + fr) * PSTR + ks * 32 + fq * 8);
                o[n] = __builtin_amdgcn_mfma_f32_16x16x32_bf16(pa, vb, o[n], 0, 0, 0);
                if (SPLIT) {
                    short8 vl = *(const short8*)(VT + 64 * PSTR + (n * 16 + fr) * PSTR + ks * 32 + fq * 8);
                    o[n] = __builtin_amdgcn_mfma_f32_16x16x32_bf16(pa, vl, o[n], 0, 0, 0);
                    o[n] = __builtin_amdgcn_mfma_f32_16x16x32_bf16(pl2, vb, o[n], 0, 0, 0);
                }
            }
        }
#pragma unroll
        for (int n = 0; n < 4; n++) {
#pragma unroll
            for (int r = 0; r < 4; r++) {
                int row = qt * 16 + fq * 4 + r;
                if (row < S) {
                    size_t oidx = ((size_t)b * S + row) * 768 + (size_t)h * 64 + n * 16 + fr;
                    float vv = o[n][r];
                    unsigned short hh = f2bf(vv);
                    oh[oidx] = hh;
                    if (SPLIT) ol[oidx] = f2bf(vv - bf2f(hh));
                }
            }
        }
    }
}

// ---------------------------------------------------------------- prune machinery
__global__ __launch_bounds__(256) void normsq_k(const float* __restrict__ x, float* __restrict__ norms)
{
    const float* xr = x + (size_t)blockIdx.x * 768;
    int t = threadIdx.x;
    float v0 = xr[t], v1 = xr[t + 256], v2 = xr[t + 512];
    float ss = v0 * v0 + v1 * v1 + v2 * v2;
#pragma unroll
    for (int o = 32; o; o >>= 1) ss += __shfl_xor(ss, o);
    __shared__ float r1[4];
    if ((t & 63) == 0) r1[t >> 6] = ss;
    __syncthreads();
    if (t == 0) norms[blockIdx.x] = r1[0] + r1[1] + r1[2] + r1[3];
}

__global__ __launch_bounds__(256) void topk_k(const float* __restrict__ norms,
                                              int* __restrict__ idxmap, int* __restrict__ cnt)
{
    int b = blockIdx.x, t = threadIdx.x;
    __shared__ float n[NTOK];
    __shared__ unsigned char kp[NTOK];
    if (t < NTOK) n[t] = norms[b * NTOK + t];
    __syncthreads();
    if (t < NTOK) {
        float me = n[t];
        int rank = 0;
        for (int j = 0; j < NTOK; j++) rank += (n[j] > me) || (n[j] == me && j < t);
        kp[t] = (rank < 98) || (t == 0);
    }
    __syncthreads();
    if (t == 0) {
        int c = 0;
        for (int s = 0; s < NTOK; s++) if (kp[s]) idxmap[b * SL + c++] = s;
        cnt[b] = c;
        for (int j = c; j < SL; j++) idxmap[b * SL + j] = 0;
    }
}

__global__ __launch_bounds__(256) void gather_k(const float* __restrict__ x, const int* __restrict__ idxmap,
                                                const int* __restrict__ cnt, float* __restrict__ xl)
{
    int j = blockIdx.x, b = blockIdx.y;
    size_t dst = ((size_t)b * SL + j) * 768;
    if (j < cnt[b]) {
        int s = idxmap[b * SL + j];
        size_t src = ((size_t)b * NTOK + s) * 768;
        for (int d = threadIdx.x; d < 768; d += 256) xl[dst + d] = x[src + d];
    } else {
        for (int d = threadIdx.x; d < 768; d += 256) xl[dst + d] = 0.f;
    }
}

// ---------------------------------------------------------------- launch
extern "C" void kernel_launch(void* const* d_in, const int* in_sizes, int n_in,
                              void* d_out, int out_size, void* d_ws, size_t ws_size,
                              hipStream_t stream)
{
    const float* images  = (const float*)d_in[0];
    const float* patch_w = (const float*)d_in[1];
    const float* patch_b = (const float*)d_in[2];
    const float* cls_tok = (const float*)d_in[3];
    const float* pos_emb = (const float*)d_in[4];
    const float* ln1_g   = (const float*)d_in[5];
    const float* ln1_b   = (const float*)d_in[6];
    const float* qkv_w   = (const float*)d_in[7];
    const float* qkv_b   = (const float*)d_in[8];
    const float* proj_w  = (const float*)d_in[9];
    const float* proj_b  = (const float*)d_in[10];
    const float* ln2_g   = (const float*)d_in[11];
    const float* ln2_b   = (const float*)d_in[12];
    const float* fc1_w   = (const float*)d_in[13];
    const float* fc1_b   = (const float*)d_in[14];
    const float* fc2_w   = (const float*)d_in[15];
    const float* fc2_b   = (const float*)d_in[16];
    const float* norm_g  = (const float*)d_in[17];
    const float* norm_b  = (const float*)d_in[18];
    const float* head_w  = (const float*)d_in[19];
    const float* head_b  = (const float*)d_in[20];
    float* outp = (float*)d_out;

    char* W = (char*)d_ws;
    float* x = (float*)W;                                       // 38,731,776
    unsigned short* hbh = (unsigned short*)(W + 38731776);
    unsigned short* hbl = hbh + 9682944;
    char* R = W + 77463552;
    unsigned short* wbh = (unsigned short*)(W + 232390656);
    unsigned short* wbl = wbh + 7077888;
    unsigned short* pwh = (unsigned short*)(W + 260702208);
    unsigned short* pwl = pwh + 589824;
    unsigned short* hwb = (unsigned short*)(W + 263061504);
    float* norms = (float*)(W + 264634368);
    unsigned short* clsb = (unsigned short*)(W + 264684800);
    int* idxmap = (int*)(W + 264881408);
    int* cnt    = (int*)(W + 264906752);

    unsigned short* ph  = (unsigned short*)R;
    unsigned short* plo = ph + 9633792;
    float* emb = (float*)(R + 38535168);
    unsigned short* qkh = (unsigned short*)R;
    unsigned short* qkl = qkh + 29048832;
    unsigned short* ffh = (unsigned short*)R;
    unsigned short* ffl = ffh + 38731776;
    float* xl = (float*)(R + 41943040);

    const int LDS_EARLY = (2 * 64 * 232 + 4 * 2 * 16 * 232) * 2;   // 118,784
    const int LDS_LATE  = (1 * 64 * 136 + 4 * 1 * 16 * 136) * 2;   // 34,816
    (void)hipFuncSetAttribute(reinterpret_cast<const void*>(&attn2_k<1, 197, 13, 7, 232>),
                              hipFuncAttributeMaxDynamicSharedMemorySize, LDS_EARLY);
    (void)hipFuncSetAttribute(reinterpret_cast<const void*>(&attn2_k<0, 99, 7, 4, 136>),
                              hipFuncAttributeMaxDynamicSharedMemorySize, LDS_LATE);

    const int nR1 = 99, nRm1 = 13;     // M = 12608
    const int nRp = 98, nRmp = 13;     // patch M = 12544
    const int nR2 = 50, nRm2 = 7;      // M = 6336

    // ---- patch embed (split) ----
    cvt_simple_k<1><<<576, 256, 0, stream>>>(patch_w, pwh, pwl, 147456);
    patch_extract2_k<<<dim3(196, NB), 256, 0, stream>>>(images, ph, plo);
    mgemm_k<1, 0, 0, 2><<<8 * nRmp * 6, 256, 0, stream>>>(ph, plo, pwh, pwl, patch_b, nullptr,
        nullptr, nullptr, emb, 12544, 768, 768, nRp, 6, nRmp);
    assemble_k<<<dim3(NTOK, NB), 256, 0, stream>>>(emb, cls_tok, pos_emb, x);

    const int M1 = NB * NTOK;   // 12608
    for (int i = 0; i < 4; i++) {
        cvt_layer_k<1><<<6912, 256, 0, stream>>>(qkv_w + (size_t)i * 1769472, proj_w + (size_t)i * 589824,
                                                 fc1_w + (size_t)i * 2359296, fc2_w + (size_t)i * 2359296,
                                                 wbh, wbl);
        ln2_k<2><<<M1, 256, 0, stream>>>(x, hbh, hbl, ln1_g + (size_t)i * 768, ln1_b + (size_t)i * 768, 768);
        mgemm_k<1, 0, 2, 1><<<8 * nRm1 * 18, 256, 0, stream>>>(hbh, hbl, wbh, wbl,
            qkv_b + (size_t)i * 2304, nullptr, qkh, qkl, nullptr, M1, 2304, 768, nR1, 18, nRm1);
        attn2_k<1, 197, 13, 7, 232><<<dim3(NHEAD, NB), 256, LDS_EARLY, stream>>>(qkh, qkl, hbh, hbl, nullptr);
        mgemm_k<1, 2, 0, 2><<<8 * nRm1 * 6, 256, 0, stream>>>(hbh, hbl, wbh + 1769472, wbl + 1769472,
            proj_b + (size_t)i * 768, x, nullptr, nullptr, x, M1, 768, 768, nR1, 6, nRm1);
        ln2_k<2><<<M1, 256, 0, stream>>>(x, hbh, hbl, ln2_g + (size_t)i * 768, ln2_b + (size_t)i * 768, 768);
        mgemm_k<1, 1, 2, 1><<<8 * nRm1 * 24, 256, 0, stream>>>(hbh, hbl, wbh + 2359296, wbl + 2359296,
            fc1_b + (size_t)i * 3072, nullptr, ffh, ffl, nullptr, M1, 3072, 768, nR1, 24, nRm1);
        mgemm_k<1, 2, 0, 2><<<8 * nRm1 * 6, 256, 0, stream>>>(ffh, ffl, wbh + 4718592, wbl + 4718592,
            fc2_b + (size_t)i * 768, x, nullptr, nullptr, x, M1, 768, 3072, nR1, 6, nRm1);
    }

    // ---- prune + compact ----
    normsq_k<<<M1, 256, 0, stream>>>(x, norms);
    topk_k<<<NB, 256, 0, stream>>>(norms, idxmap, cnt);
    gather_k<<<dim3(SL, NB), 256, 0, stream>>>(x, idxmap, cnt, xl);

    const int M2 = NB * SL;     // 6336
    for (int i = 4; i < 12; i++) {
        cvt_layer_k<0><<<6912, 256, 0, stream>>>(qkv_w + (size_t)i * 1769472, proj_w + (size_t)i * 589824,
                                                 fc1_w + (size_t)i * 2359296, fc2_w + (size_t)i * 2359296,
                                                 wbh, nullptr);
        ln2_k<1><<<M2, 256, 0, stream>>>(xl, hbh, nullptr, ln1_g + (size_t)i * 768, ln1_b + (size_t)i * 768, 768);
        mgemm_k<0, 0, 1, 1><<<8 * nRm2 * 18, 256, 0, stream>>>(hbh, nullptr, wbh, nullptr,
            qkv_b + (size_t)i * 2304, nullptr, qkh, nullptr, nullptr, M2, 2304, 768, nR2, 18, nRm2);
        attn2_k<0, 99, 7, 4, 136><<<dim3(NHEAD, NB), 256, LDS_LATE, stream>>>(qkh, nullptr, hbl, nullptr, cnt);
        mgemm_k<0, 2, 0, 2><<<8 * nRm2 * 6, 256, 0, stream>>>(hbl, nullptr, wbh + 1769472, nullptr,
            proj_b + (size_t)i * 768, xl, nullptr, nullptr, xl, M2, 768, 768, nR2, 6, nRm2);
        ln2_k<1><<<M2, 256, 0, stream>>>(xl, hbh, nullptr, ln2_g + (size_t)i * 768, ln2_b + (size_t)i * 768, 768);
        mgemm_k<0, 1, 1, 1><<<8 * nRm2 * 24, 256, 0, stream>>>(hbh, nullptr, wbh + 2359296, nullptr,
            fc1_b + (size_t)i * 3072, nullptr, ffh, nullptr, nullptr, M2, 3072, 768, nR2, 24, nRm2);
        mgemm_k<0, 2, 0, 2><<<8 * nRm2 * 6, 256, 0, stream>>>(ffh, nullptr, wbh + 4718592, nullptr,
            fc2_b + (size_t)i * 768, xl, nullptr, nullptr, xl, M2, 768, 3072, nR2, 6, nRm2);
    }

    // ---- final LN(CLS) + head ----
    ln2_k<1><<<NB, 256, 0, stream>>>(xl, clsb, nullptr, norm_g, norm_b, (size_t)SL * 768);
    cvt_simple_k<0><<<750, 256, 0, stream>>>(head_w, hwb, nullptr, 192000);
    mgemm_k<0, 0, 0, 0><<<8, 256, 0, stream>>>(clsb, nullptr, hwb, nullptr,
        head_b, nullptr, nullptr, nullptr, outp, 64, 1000, 768, 1, 8, 1);
}